// Round 7
// baseline (149.541 us; speedup 1.0000x reference)
//
#include <hip/hip_runtime.h>

// Problem constants
#define EMBED 1024
#define NHEAD 16
#define HD    64
#define SEQ   2048
#define BATCH 2
#define ROWS  (BATCH * SEQ)  // 4096

typedef float f32x4 __attribute__((ext_vector_type(4)));
typedef short short8 __attribute__((ext_vector_type(8)));
typedef short short4v __attribute__((ext_vector_type(4)));
typedef unsigned short u16x4 __attribute__((ext_vector_type(4)));
typedef unsigned short u16x8 __attribute__((ext_vector_type(8)));
typedef unsigned u32x4 __attribute__((ext_vector_type(4)));
typedef unsigned u32x2 __attribute__((ext_vector_type(2)));

#define LOG2E 1.4426950408889634f

__device__ __forceinline__ unsigned short f2bf(float f) {
  unsigned int u = __builtin_bit_cast(unsigned int, f);
  u += 0x7fffu + ((u >> 16) & 1u);  // round-to-nearest-even
  return (unsigned short)(u >> 16);
}

// pack 2 f32 -> 2 bf16 in one u32 (RNE), gfx950
__device__ __forceinline__ unsigned cvtpk(float lo, float hi) {
  unsigned r;
  asm("v_cvt_pk_bf16_f32 %0, %1, %2" : "=v"(r) : "v"(lo), "v"(hi));
  return r;
}

#if __has_builtin(__builtin_amdgcn_exp2f)
#define EXP2(x) __builtin_amdgcn_exp2f(x)
#else
#define EXP2(x) exp2f(x)
#endif

__device__ __forceinline__ void gll16(const void* g, const void* l) {
  __builtin_amdgcn_global_load_lds(
      (const __attribute__((address_space(1))) unsigned int*)g,
      (__attribute__((address_space(3))) unsigned int*)l, 16, 0, 0);
}

__device__ __forceinline__ unsigned lds_addr(const void* p) {
  return (unsigned)(size_t)(__attribute__((address_space(3))) const void*)p;
}

// ---------------------------------------------------------------- cvt: 4 weights (y<4); x->bf16 + FUSED fp32 gate (y==4)
// y==4: block b holds rows {b, 1024+b, 2048+b, 3072+b}. Stage fp32 rows to LDS; wave w computes
// gate for row w*1024+b: lane=(chunk<<4)|head, 64 f32x4 FMA (LDS x, L2-hot Wf), shfl_xor reduce.
// Exact fp32 (replaces split-bf16 gate kernel). Also zero-inits qkmax (block 0).
__global__ __launch_bounds__(256) void cvt_all_kernel(
    const float* __restrict__ x,
    const float* __restrict__ w0, const float* __restrict__ w1,
    const float* __restrict__ w2, const float* __restrict__ w3,
    const float* __restrict__ wf,
    unsigned short* __restrict__ xo,
    unsigned short* __restrict__ o0, unsigned short* __restrict__ o1,
    unsigned short* __restrict__ o2, unsigned short* __restrict__ o3,
    unsigned* __restrict__ qkmaxu, float* __restrict__ carr) {
  __shared__ float xrow[4][1024];
  const int y = blockIdx.y;
  if (y < 4) {
    const float* in = (y == 0) ? w0 : (y == 1) ? w1 : (y == 2) ? w2 : w3;
    unsigned short* out = (y == 0) ? o0 : (y == 1) ? o1 : (y == 2) ? o2 : o3;
    const int i = blockIdx.x * 256 + threadIdx.x;  // 262144 items
    f32x4 v = reinterpret_cast<const f32x4*>(in)[i];
    u16x4 o;
#pragma unroll
    for (int e = 0; e < 4; ++e) o[e] = f2bf(v[e]);
    reinterpret_cast<u16x4*>(out)[i] = o;
  } else {
    const int b = blockIdx.x, t = threadIdx.x;
    if (b == 0 && t < 64) qkmaxu[t] = 0u;  // zero-init for atomicMax (workspace is poisoned)
#pragma unroll
    for (int e = 0; e < 4; ++e) {
      const int i = b * 256 + t + e * 262144;  // f32x4 index == (e*1024+b)*256 + t
      f32x4 v = reinterpret_cast<const f32x4*>(x)[i];
      u16x4 h;
#pragma unroll
      for (int q = 0; q < 4; ++q) h[q] = f2bf(v[q]);
      reinterpret_cast<u16x4*>(xo)[i] = h;
      *reinterpret_cast<f32x4*>(&xrow[e][t * 4]) = v;
    }
    __syncthreads();
    // gate: wave wv owns row wv*1024 + b
    const int wv = t >> 6, lane = t & 63;
    const int hh = lane & 15, ck = lane >> 4;
    const f32x4* xs = reinterpret_cast<const f32x4*>(&xrow[wv][ck * 256]);
    const f32x4* wp = reinterpret_cast<const f32x4*>(wf + (size_t)hh * EMBED + ck * 256);
    f32x4 a4 = {};
#pragma unroll 8
    for (int k = 0; k < 64; ++k) a4 += xs[k] * wp[k];
    float s = (a4[0] + a4[1]) + (a4[2] + a4[3]);
    s += __shfl_xor(s, 16);
    s += __shfl_xor(s, 32);
    if (ck == 0) {
      const float ls = (fminf(s, 0.f) - log1pf(__expf(-fabsf(s)))) * LOG2E;
      const int row = wv * 1024 + b;
      const int bb = row >> 11, nn = row & (SEQ - 1);
      carr[(size_t)(bb * NHEAD + hh) * SEQ + nn] = ls;
    }
  }
}

// ---------------------------------------------------------------- GEMM C = A @ B^T, 128x128 tile, BK=64 (kept for Wo)
template <bool OUT_BF16>
__global__ __launch_bounds__(256) void gemm3_kernel(
    const unsigned short* __restrict__ A,
    const unsigned short* __restrict__ B0, const unsigned short* __restrict__ B1,
    const unsigned short* __restrict__ B2,
    void* __restrict__ C0, void* __restrict__ C1, void* __restrict__ C2) {
  __shared__ unsigned short Asm[128 * 64];
  __shared__ unsigned short Bsm[128 * 64];
  const int tid = threadIdx.x, wid = tid >> 6, lane = tid & 63;
  const int g = lane >> 4, l16 = lane & 15;
  const int wr = wid >> 1, wc = wid & 1;
  const int mb = blockIdx.y;
  const int nb = blockIdx.x;
  const int which = nb >> 3;
  const int col0 = (nb & 7) * 128;
  const unsigned short* Bp = (which == 0) ? B0 : (which == 1) ? B1 : B2;
  void* Cp = (which == 0) ? C0 : (which == 1) ? C1 : C2;

  f32x4 acc[4][4] = {};

  for (int k0 = 0; k0 < EMBED; k0 += 64) {
    __syncthreads();
#pragma unroll
    for (int q = 0; q < 4; ++q) {
      const int base = (wid * 4 + q) * 1024;
      const int off = base + lane * 16;
      const int row = off >> 7;
      const int colel = (off & 127) >> 1;
      gll16(A + (size_t)(mb * 128 + row) * EMBED + k0 + colel, (const char*)Asm + base);
      gll16(Bp + (size_t)(col0 + row) * EMBED + k0 + colel, (const char*)Bsm + base);
    }
    __syncthreads();

#pragma unroll
    for (int kc = 0; kc < 2; ++kc) {
      short8 am[4], bm[4];
#pragma unroll
      for (int mi = 0; mi < 4; ++mi)
        am[mi] = *reinterpret_cast<const short8*>(&Asm[(wr * 64 + mi * 16 + l16) * 64 + kc * 32 + g * 8]);
#pragma unroll
      for (int ni = 0; ni < 4; ++ni)
        bm[ni] = *reinterpret_cast<const short8*>(&Bsm[(wc * 64 + ni * 16 + l16) * 64 + kc * 32 + g * 8]);
#pragma unroll
      for (int mi = 0; mi < 4; ++mi)
#pragma unroll
        for (int ni = 0; ni < 4; ++ni)
          acc[mi][ni] = __builtin_amdgcn_mfma_f32_16x16x32_bf16(am[mi], bm[ni], acc[mi][ni], 0, 0, 0);
    }
  }

#pragma unroll
  for (int mi = 0; mi < 4; ++mi)
#pragma unroll
    for (int ni = 0; ni < 4; ++ni)
#pragma unroll
      for (int r = 0; r < 4; ++r) {
        const int m = mb * 128 + wr * 64 + mi * 16 + g * 4 + r;
        const int n = col0 + wc * 64 + ni * 16 + l16;
        if (OUT_BF16)
          ((unsigned short*)Cp)[(size_t)m * EMBED + n] = f2bf(acc[mi][ni][r]);
        else
          ((float*)Cp)[(size_t)m * EMBED + n] = acc[mi][ni][r];
      }
}

// ---------------------------------------------------------------- 256x256 8-phase GEMM C = A @ B^T (QKV path)
// 8 waves (2M x 4N), BK=64, 2 K-tiles per iteration, counted vmcnt(4) at phases 4/8,
// LDS XOR-swizzle byte ^= (row&7)<<4 (write side: pre-swizzled gll16 source; read side: swizzled ds_read addr).
// LDS: [dbuf][A=0/B=1][half][128*64] bf16 = 128 KiB, double-buffered by K-tile parity.
// XCD swizzle: xcd = linear_id & 7 owns 2 consecutive mb rows x all 12 nb -> A-panels L2-hot per XCD.
// FUSED maxabs: wave's output cols span ONE head; wave-reduce max|bf16(acc)|, atomicMax qkmaxu.
#define BAR() asm volatile("s_barrier" ::: "memory")
#define LGKM0()                                              \
  do {                                                       \
    asm volatile("s_waitcnt lgkmcnt(0)" ::: "memory");       \
    __builtin_amdgcn_sched_barrier(0);                       \
  } while (0)
#define VM(n_) asm volatile("s_waitcnt vmcnt(" #n_ ")" ::: "memory")

template <bool OUT_BF16>
__global__ __launch_bounds__(512, 2) void gemm256_kernel(
    const unsigned short* __restrict__ A,
    const unsigned short* __restrict__ B0, const unsigned short* __restrict__ B1,
    const unsigned short* __restrict__ B2,
    void* __restrict__ C0, void* __restrict__ C1, void* __restrict__ C2,
    unsigned* __restrict__ qkmaxu) {
  __shared__ unsigned short sm[2][2][2][8192];  // [dbuf][AB][half][row*64+col] : 128 KiB
  const int tid = threadIdx.x, wid = tid >> 6, lane = tid & 63;
  const int g = lane >> 4, l16 = lane & 15;
  const int wr = wid >> 2, wcol = wid & 3;  // wave tile: rows wr*128.. , cols wcol*64..
  // XCD-aware bijective swizzle of the 192-block grid (8 XCDs x 24 blocks = 2 mb x 12 nb each)
  const int id = blockIdx.y * 12 + blockIdx.x;
  const int xcd = id & 7, loc = id >> 3;  // loc in [0,24)
  const int mb = (xcd << 1) + (loc >= 12 ? 1 : 0);
  const int nb = (loc >= 12) ? (loc - 12) : loc;
  const int which = nb >> 2;
  const int col0 = (nb & 3) * 256;
  const unsigned short* Bp = (which == 0) ? B0 : (which == 1) ? B1 : B2;
  void* Cp = (which == 0) ? C0 : (which == 1) ? C1 : C2;

  // ---- staging invariants (pre-swizzled global source, linear LDS dest) ----
  const int lane8 = lane & 7, laneHi = lane >> 3;
  const int colel = (lane8 ^ laneHi) * 8;  // source col element (inverse swizzle; row&7 == laneHi)
  int soff[2];
#pragma unroll
  for (int q = 0; q < 2; ++q)
    soff[q] = (q * 64 + wid * 8 + laneHi) * EMBED + colel;  // element offset within a half-panel
  const unsigned short* Ag = A + (size_t)(mb * 256) * EMBED;
  const unsigned short* Bg = Bp + (size_t)col0 * EMBED;

  // ---- ds_read invariants (swizzled column offsets; row&7 == l16&7 for all frag rows) ----
  const int sw = (l16 & 7) << 4;
  const int cs0 = (0 | (g * 16)) ^ sw;   // kc=0
  const int cs1 = (64 | (g * 16)) ^ sw;  // kc=1
  const char* smB = (const char*)sm;
  const int aBase = wr * 16384 + l16 * 128;
  const int bBase = 32768 + (wcol >> 1) * 16384 + (wcol & 1) * 8192 + l16 * 128;

#define STG(buf_, ab_, half_, gsrc_, t_)                                               \
  do {                                                                                 \
    const unsigned short* gp_ = (gsrc_) + (size_t)(half_) * (128 * EMBED) + (t_) * 64; \
    char* lp_ = (char*)sm + (buf_) * 65536 + (ab_) * 32768 + (half_) * 16384 + wid * 1024; \
    gll16(gp_ + soff[0], lp_);                                                         \
    gll16(gp_ + soff[1], lp_ + 8192);                                                  \
  } while (0)

#define RD_A(buf_, row_, kc_) \
  (*reinterpret_cast<const short8*>(smB + (buf_) * 65536 + aBase + (row_) * 2048 + ((kc_) ? cs1 : cs0)))
#define RD_B(buf_, row_, kc_) \
  (*reinterpret_cast<const short8*>(smB + (buf_) * 65536 + bBase + (row_) * 2048 + ((kc_) ? cs1 : cs0)))

#define QUAD(mg_, ng_)                                                                   \
  do {                                                                                   \
    __builtin_amdgcn_s_setprio(1);                                                       \
    _Pragma("unroll") for (int kc_ = 0; kc_ < 2; ++kc_)                                  \
      _Pragma("unroll") for (int mi_ = 0; mi_ < 4; ++mi_)                                \
        _Pragma("unroll") for (int nj_ = 0; nj_ < 2; ++nj_)                              \
          acc[(mg_) * 4 + mi_][(ng_) * 2 + nj_] = __builtin_amdgcn_mfma_f32_16x16x32_bf16( \
              fa[mi_][kc_], fb[(ng_) * 2 + nj_][kc_], acc[(mg_) * 4 + mi_][(ng_) * 2 + nj_], 0, 0, 0); \
    __builtin_amdgcn_s_setprio(0);                                                       \
  } while (0)

  // 4 phases of one K-tile: ph1 {12 ds_reads, stage, Q(0,0)}, ph2 {4, stage, Q(0,1)},
  // ph3 {8, stage, Q(1,0)}, ph4 {stage+vmcnt, Q(1,1)}
#define KTILE4(BUF_, STG_P1, STG_P2, STG_P3, STG_P4_VM)                                  \
  do {                                                                                   \
    _Pragma("unroll") for (int mi_ = 0; mi_ < 4; ++mi_) {                                \
      fa[mi_][0] = RD_A(BUF_, mi_, 0);                                                   \
      fa[mi_][1] = RD_A(BUF_, mi_, 1);                                                   \
    }                                                                                    \
    _Pragma("unroll") for (int ni_ = 0; ni_ < 2; ++ni_) {                                \
      fb[ni_][0] = RD_B(BUF_, ni_, 0);                                                   \
      fb[ni_][1] = RD_B(BUF_, ni_, 1);                                                   \
    }                                                                                    \
    STG_P1;                                                                              \
    asm volatile("s_waitcnt lgkmcnt(8)" ::: "memory");                                   \
    BAR();                                                                               \
    LGKM0();                                                                             \
    QUAD(0, 0);                                                                          \
    BAR();                                                                               \
    _Pragma("unroll") for (int ni_ = 0; ni_ < 2; ++ni_) {                                \
      fb[2 + ni_][0] = RD_B(BUF_, 2 + ni_, 0);                                           \
      fb[2 + ni_][1] = RD_B(BUF_, 2 + ni_, 1);                                           \
    }                                                                                    \
    STG_P2;                                                                              \
    BAR();                                                                               \
    LGKM0();                                                                             \
    QUAD(0, 1);                                                                          \
    BAR();                                                                               \
    _Pragma("unroll") for (int mi_ = 0; mi_ < 4; ++mi_) {                                \
      fa[mi_][0] = RD_A(BUF_, 4 + mi_, 0);                                               \
      fa[mi_][1] = RD_A(BUF_, 4 + mi_, 1);                                               \
    }                                                                                    \
    STG_P3;                                                                              \
    BAR();                                                                               \
    LGKM0();                                                                             \
    QUAD(1, 0);                                                                          \
    BAR();                                                                               \
    STG_P4_VM;                                                                           \
    BAR();                                                                               \
    QUAD(1, 1);                                                                          \
    BAR();                                                                               \
  } while (0)

  short8 fa[4][2], fb[4][2];
  f32x4 acc[8][4] = {};

  // ---- prologue: tile0 fully (A0,B0,A1,B1) + tile1 B-halves; wait tile0, keep 2 halves in flight ----
  STG(0, 0, 0, Ag, 0);
  STG(0, 1, 0, Bg, 0);
  STG(0, 0, 1, Ag, 0);
  STG(0, 1, 1, Bg, 0);
  STG(1, 1, 0, Bg, 1);
  STG(1, 1, 1, Bg, 1);
  VM(4);
  BAR();

  // ---- main loop: 16 K-tiles, 2 per iteration (buf0 then buf1), 8 phases ----
  for (int it = 0; it < 8; ++it) {
    const int t1 = 2 * it + 1, t2 = 2 * it + 2, t3 = 2 * it + 3;
    const bool nl = (it < 7);
    // K-tile 2i (buf0); stage t1's A-halves (buf1) then t2's B-halves (buf0, released after ph2)
    KTILE4(0,
           STG(1, 0, 0, Ag, t1),
           STG(1, 0, 1, Ag, t1),
           if (nl) STG(0, 1, 0, Bg, t2),
           if (nl) { STG(0, 1, 1, Bg, t2); VM(4); } else VM(0));
    // K-tile 2i+1 (buf1); stage t2's A-halves (buf0, released after ph3) then t3's B-halves (buf1)
    KTILE4(1,
           if (nl) STG(0, 0, 0, Ag, t2),
           if (nl) STG(0, 0, 1, Ag, t2),
           if (nl) STG(1, 1, 0, Bg, t3),
           if (nl) { STG(1, 1, 1, Bg, t3); VM(4); });
  }

  // ---- epilogue (+ fused maxabs for Q/K tensors) ----
  unsigned mxv = 0;
#pragma unroll
  for (int mi = 0; mi < 8; ++mi)
#pragma unroll
    for (int ni = 0; ni < 4; ++ni)
#pragma unroll
      for (int r = 0; r < 4; ++r) {
        const int m = mb * 256 + wr * 128 + mi * 16 + g * 4 + r;
        const int n = col0 + wcol * 64 + ni * 16 + l16;
        if (OUT_BF16) {
          const unsigned short bv = f2bf(acc[mi][ni][r]);
          ((unsigned short*)Cp)[(size_t)m * EMBED + n] = bv;
          const unsigned a = bv & 0x7fffu;
          mxv = a > mxv ? a : mxv;
        } else {
          ((float*)Cp)[(size_t)m * EMBED + n] = acc[mi][ni][r];
        }
      }
  if (OUT_BF16 && which < 2) {
#pragma unroll
    for (int mm = 1; mm < 64; mm <<= 1) {
      const unsigned o = __shfl_xor(mxv, mm);
      mxv = o > mxv ? o : mxv;
    }
    if (lane == 0) {
      const int bbat = (mb >= 8) ? 1 : 0;
      const int head = (nb & 3) * 4 + wcol;
      const int idx = which * 32 + bbat * 16 + head;
      atomicMax(&qkmaxu[idx], mxv << 16);  // positive-float bits: uint max == float max
    }
  }
#undef STG
#undef RD_A
#undef RD_B
#undef QUAD
#undef KTILE4
}
#undef BAR
#undef LGKM0
#undef VM

// ---------------------------------------------------------------- cumsum per (b,h)
__global__ void cumsum_kernel(float* __restrict__ c) {
  const int bh = blockIdx.x;
  const int lane = threadIdx.x;  // 64
  float* p = c + (size_t)bh * SEQ;
  f32x4 vv[8];
  f32x4* vp = reinterpret_cast<f32x4*>(p + lane * 32);
#pragma unroll
  for (int q = 0; q < 8; ++q) vv[q] = vp[q];
  float run = 0.f;
#pragma unroll
  for (int q = 0; q < 8; ++q)
#pragma unroll
    for (int e = 0; e < 4; ++e) { run += vv[q][e]; vv[q][e] = run; }
  float s = run;
#pragma unroll
  for (int off = 1; off < 64; off <<= 1) {
    float u = __shfl_up(s, off);
    if (lane >= off) s += u;
  }
  const float excl = s - run;
#pragma unroll
  for (int q = 0; q < 8; ++q)
#pragma unroll
    for (int e = 0; e < 4; ++e) vv[q][e] += excl;
#pragma unroll
  for (int q = 0; q < 8; ++q) vp[q] = vv[q];
}

// ---------------------------------------------------------------- flash attention, swapped-QK^T, XCD-clustered,
// DECAY-SKIP: tile t is processed only if its rigorous upper bound can matter:
//   contribution(t)/l_ <= 2^( c2[i_min]-c2[t_end] + 2U + 6 ),  U = 64*|q|inf*|k|inf*0.125*LOG2E
// Skip when < 2^-35 (threshold -41-2U). c2 monotone decreasing => single backward scan for t_start.
// Typical horizon ~3-4 tiles => ~5 tiles/block, uniform work, no balance tricks needed.
#define NINF (-3.0e38f)
#define SCL (0.125f * LOG2E)
#define BMARG 14.0f

#define TR_READ(dst, addr, OFF) \
  asm volatile("ds_read_b64_tr_b16 %0, %1 offset:" OFF : "=v"(dst) : "v"(addr))

__global__ __launch_bounds__(256) void fa_attn_kernel(
    const unsigned short* __restrict__ Q, const unsigned short* __restrict__ K,
    const unsigned short* __restrict__ V, const float* __restrict__ C,
    const float* __restrict__ qkmax, unsigned short* __restrict__ O) {
  __shared__ unsigned short Ksm[2][4096];  // 8KB each: [64 j][64 dh], rows XOR-swizzled
  __shared__ unsigned short Vsm[2][4096];  // 8KB each: [4 dblk][64 j][16 d] subtiled
  const int p = blockIdx.x;                 // 0..1023
  const int xcd = p & 7, s2 = p >> 3;       // 128 blocks per XCD
  const int hb = xcd * 4 + (s2 >> 5);       // (b,h) pair index (4 per XCD -> 2MB L2 set)
  const int qb = s2 & 31;
  const int hh = hb & 15, bb = hb >> 4;
  const int tid = threadIdx.x, wid = tid >> 6, lane = tid & 63;
  const int g = lane >> 4, l16 = lane & 15;
  const int i_base = qb * 64 + wid * 16;

  const float* cptr = C + (size_t)(bb * NHEAD + hh) * SEQ;

  // staging source offsets (elements, relative to tile origin), per lane
  int kOff[2], vOff[2];
#pragma unroll
  for (int qq = 0; qq < 2; ++qq) {
    const int q = wid * 2 + qq;
    {  // K: linear LDS pos pl = q*1024 + lane*16 -> row = pl>>7, swizzled source col
      const int row = q * 8 + (lane >> 3);
      const int colel = ((lane & 7) ^ (lane >> 3)) * 8;
      kOff[qq] = row * EMBED + colel;
    }
    {  // V: subtiled [dblk][j][16]
      const int dblk = q >> 1;
      const int j = (q & 1) * 32 + (lane >> 1);
      const int dlow = (lane & 1) * 8;
      vOff[qq] = j * EMBED + dblk * 16 + dlow;
    }
  }
  const unsigned short* Kbase = K + (size_t)bb * SEQ * EMBED + hh * HD;
  const unsigned short* Vbase = V + (size_t)bb * SEQ * EMBED + hh * HD;

  // K LDS read offsets (bytes), loop-invariant
  const int swz = (l16 & 7) << 4;
  const int koffB0 = ((0) | (g * 16)) ^ swz;
  const int koffB1 = ((64) | (g * 16)) ^ swz;
  const int krowB = l16 * 128;

#define STAGE(bufidx, tt)                                                              \
  do {                                                                                 \
    const unsigned short* kb_ = Kbase + (size_t)(tt) * 64 * EMBED;                     \
    const unsigned short* vb_ = Vbase + (size_t)(tt) * 64 * EMBED;                     \
    _Pragma("unroll") for (int qq = 0; qq < 2; ++qq) {                                 \
      gll16(kb_ + kOff[qq], (const char*)&Ksm[bufidx][0] + (wid * 2 + qq) * 1024);     \
      gll16(vb_ + vOff[qq], (const char*)&Vsm[bufidx][0] + (wid * 2 + qq) * 1024);     \
    }                                                                                  \
  } while (0)

  // Q B-fragments (col=i=l16, k=g*8+e), hoisted
  short8 qf0, qf1;
  {
    const unsigned short* qp = Q + (size_t)(bb * SEQ + i_base + l16) * EMBED + hh * HD + g * 8;
    qf0 = *reinterpret_cast<const short8*>(qp);
    qf1 = *reinterpret_cast<const short8*>(qp + 32);
  }
  const float c2i = cptr[i_base + l16];  // log2-domain cumsum at this lane's row i

  // decay-skip horizon: tile t alive iff c2[i_min] - c2[t*64+63] >= thr
  int t_start = qb;
  {
    const float qm = qkmax[hb];
    const float km = qkmax[32 + hb];
    const float thr = -41.f - 23.0832f * qm * km;  // -41 - 2U, U = 64*0.125*LOG2E*qm*km
    const float c2imin = cptr[qb * 64];
    while (t_start > 0 && (c2imin - cptr[t_start * 64 - 1] >= thr)) --t_start;
  }

  // analytic softmax reference: m_t = -c2(tile-end) + BMARG (monotone since c2 decreasing)
  float mc_prev = (t_start == qb) ? c2i : cptr[t_start * 64 + 63];
  float l_ = 0.f;
  f32x4 accd[4] = {};

  STAGE(0, t_start);
  __syncthreads();

  int buf = 0;
  for (int t = t_start; t <= qb; ++t) {
    if (t < qb) STAGE(buf ^ 1, t + 1);  // prefetch; drained by this iter's end barrier
    const int kv0 = t * 64;
    const bool diag = (t == qb);
    const int nj = diag ? (wid + 1) : 4;  // skip fully-masked j-blocks on diagonal

    const float mc_cur = diag ? c2i : cptr[kv0 + 63];
    const float corr = EXP2(mc_cur - mc_prev);  // <= 1; pure function of c2, no reduction
    mc_prev = mc_cur;
    const float mcB = mc_cur - BMARG;

    // S^T = K·Q^T: col=i=l16, row j = jb*16 + g*4 + r. p = 2^(qk*SCL + mcB - c2_j)
    float pf[4][4];
    float lsum = 0.f;
#pragma unroll
    for (int jb = 0; jb < 4; ++jb) {
      if (jb < nj) {
        const char* kbp = (const char*)&Ksm[buf][0] + jb * 2048 + krowB;
        short8 kf0 = *reinterpret_cast<const short8*>(kbp + koffB0);
        short8 kf1 = *reinterpret_cast<const short8*>(kbp + koffB1);
        f32x4 s = {};
        __builtin_amdgcn_s_setprio(1);
        s = __builtin_amdgcn_mfma_f32_16x16x32_bf16(kf0, qf0, s, 0, 0, 0);
        s = __builtin_amdgcn_mfma_f32_16x16x32_bf16(kf1, qf1, s, 0, 0, 0);
        __builtin_amdgcn_s_setprio(0);
        const f32x4 cv = *reinterpret_cast<const f32x4*>(&cptr[kv0 + jb * 16 + g * 4]);
#pragma unroll
        for (int r = 0; r < 4; ++r) {
          float arg = __builtin_fmaf(s[r], SCL, mcB - cv[r]);
          if (diag && jb == wid && (g * 4 + r > l16)) arg = NINF;  // causal mask
          const float pv = EXP2(arg);
          pf[jb][r] = pv;
          lsum += pv;
        }
      } else {
#pragma unroll
        for (int r = 0; r < 4; ++r) pf[jb][r] = 0.f;
      }
    }
    l_ = l_ * corr + lsum;  // lane-local partial (reduced across g at epilogue)
#pragma unroll
    for (int d = 0; d < 4; ++d) accd[d] *= corr;

    // pack P into B-frags via v_cvt_pk_bf16_f32 (k-slot (g,e) -> j = kc*32 + (e>>2)*16 + g*4 + (e&3))
    u32x4 w0, w1;
    w0[0] = cvtpk(pf[0][0], pf[0][1]); w0[1] = cvtpk(pf[0][2], pf[0][3]);
    w0[2] = cvtpk(pf[1][0], pf[1][1]); w0[3] = cvtpk(pf[1][2], pf[1][3]);
    w1[0] = cvtpk(pf[2][0], pf[2][1]); w1[1] = cvtpk(pf[2][2], pf[2][3]);
    w1[2] = cvtpk(pf[3][0], pf[3][1]); w1[3] = cvtpk(pf[3][2], pf[3][3]);
    const short8 pb0 = __builtin_bit_cast(short8, w0);
    const short8 pb1 = __builtin_bit_cast(short8, w1);

    // O^T += V^T · P : A-frags via tr-read (delivers j = jsub*16 + g*4 + r at d = l16)
    const unsigned vb0 = lds_addr(&Vsm[buf][0]) + lane * 8;
#pragma unroll
    for (int db = 0; db < 4; ++db) {
      const unsigned va = vb0 + db * 2048;
      short4v t0, t1, t2, t3;
      TR_READ(t0, va, "0");
      TR_READ(t1, va, "512");
      TR_READ(t2, va, "1024");
      TR_READ(t3, va, "1536");
      asm volatile("s_waitcnt lgkmcnt(0)" ::: "memory");
      __builtin_amdgcn_sched_barrier(0);
      short8 va0, va1;
#pragma unroll
      for (int e = 0; e < 4; ++e) {
        va0[e] = t0[e]; va0[e + 4] = t1[e];
        va1[e] = t2[e]; va1[e + 4] = t3[e];
      }
      __builtin_amdgcn_s_setprio(1);
      accd[db] = __builtin_amdgcn_mfma_f32_16x16x32_bf16(va0, pb0, accd[db], 0, 0, 0);
      accd[db] = __builtin_amdgcn_mfma_f32_16x16x32_bf16(va1, pb1, accd[db], 0, 0, 0);
      __builtin_amdgcn_s_setprio(0);
    }
    __syncthreads();  // drains vmcnt (stage t+1 done) + all waves' LDS reads of buf
    buf ^= 1;
  }

  // epilogue: reduce l_ across the 4 g-groups (same i=l16), then store O[i][d]
  l_ += __shfl_xor(l_, 16);
  l_ += __shfl_xor(l_, 32);
  const float inv = 1.0f / l_;
  unsigned short* op = O + (size_t)(bb * SEQ + i_base + l16) * EMBED + hh * HD;
#pragma unroll
  for (int db = 0; db < 4; ++db) {
    u32x2 o;
    o[0] = cvtpk(accd[db][0] * inv, accd[db][1] * inv);
    o[1] = cvtpk(accd[db][2] * inv, accd[db][3] * inv);
    *reinterpret_cast<u32x2*>(op + db * 16 + g * 4) = o;
  }
#undef STAGE
}

// ---------------------------------------------------------------- launcher
extern "C" void kernel_launch(void* const* d_in, const int* in_sizes, int n_in,
                              void* d_out, int out_size, void* d_ws, size_t ws_size,
                              hipStream_t stream) {
  const float* x = (const float*)d_in[0];
  const float* Wq = (const float*)d_in[1];
  const float* Wk = (const float*)d_in[2];
  const float* Wv = (const float*)d_in[3];
  const float* Wo = (const float*)d_in[4];
  const float* Wf = (const float*)d_in[5];
  float* out = (float*)d_out;

  char* ws = (char*)d_ws;
  const size_t SZ_X = (size_t)ROWS * EMBED * sizeof(unsigned short);
  const size_t SZ_W = (size_t)EMBED * EMBED * sizeof(unsigned short);
  unsigned short* xb = (unsigned short*)ws;   ws += SZ_X;
  unsigned short* Wqb = (unsigned short*)ws;  ws += SZ_W;
  unsigned short* Wkb = (unsigned short*)ws;  ws += SZ_W;
  unsigned short* Wvb = (unsigned short*)ws;  ws += SZ_W;
  unsigned short* Wob = (unsigned short*)ws;  ws += SZ_W;
  unsigned short* Qb = (unsigned short*)ws;   ws += SZ_X;
  unsigned short* Kb = (unsigned short*)ws;   ws += SZ_X;
  unsigned short* Vb = (unsigned short*)ws;   ws += SZ_X;
  unsigned short* attnb = (unsigned short*)ws; ws += SZ_X;
  float* carr = (float*)ws;                   ws += (size_t)BATCH * NHEAD * SEQ * sizeof(float);
  float* qkmax = (float*)ws;                  ws += 64 * sizeof(float);

  // cvt weights + x->bf16 + fused fp32 gate + qkmax zero-init
  cvt_all_kernel<<<dim3(1024, 5), 256, 0, stream>>>(
      x, Wq, Wk, Wv, Wo, Wf, xb, Wqb, Wkb, Wvb, Wob, (unsigned*)qkmax, carr);

  cumsum_kernel<<<BATCH * NHEAD, 64, 0, stream>>>(carr);

  // QKV projections: 256x256 8-phase kernel, XCD-swizzled grid, fused maxabs
  gemm256_kernel<true><<<dim3(12, 16), 512, 0, stream>>>(
      xb, Wqb, Wkb, Wvb, Qb, Kb, Vb, (unsigned*)qkmax);

  // attention: QBLK=64, 1024 blocks (128 per XCD)
  fa_attn_kernel<<<1024, 256, 0, stream>>>(Qb, Kb, Vb, carr, qkmax, attnb);

  gemm3_kernel<false><<<dim3(8, 32), 256, 0, stream>>>(
      attnb, Wob, Wob, Wob, out, out, out);
}

// Round 8
// 101.850 us; speedup vs baseline: 1.4682x; 1.4682x over previous
//
#include <hip/hip_runtime.h>

// Problem constants
#define EMBED 1024
#define NHEAD 16
#define HD    64
#define SEQ   2048
#define BATCH 2
#define ROWS  (BATCH * SEQ)  // 4096

typedef float f32x4 __attribute__((ext_vector_type(4)));
typedef short short8 __attribute__((ext_vector_type(8)));
typedef short short4v __attribute__((ext_vector_type(4)));
typedef unsigned short u16x4 __attribute__((ext_vector_type(4)));
typedef unsigned short u16x8 __attribute__((ext_vector_type(8)));
typedef unsigned u32x4 __attribute__((ext_vector_type(4)));
typedef unsigned u32x2 __attribute__((ext_vector_type(2)));

#define LOG2E 1.4426950408889634f

__device__ __forceinline__ unsigned short f2bf(float f) {
  unsigned int u = __builtin_bit_cast(unsigned int, f);
  u += 0x7fffu + ((u >> 16) & 1u);  // round-to-nearest-even
  return (unsigned short)(u >> 16);
}

// pack 2 f32 -> 2 bf16 in one u32 (RNE), gfx950
__device__ __forceinline__ unsigned cvtpk(float lo, float hi) {
  unsigned r;
  asm("v_cvt_pk_bf16_f32 %0, %1, %2" : "=v"(r) : "v"(lo), "v"(hi));
  return r;
}

#if __has_builtin(__builtin_amdgcn_exp2f)
#define EXP2(x) __builtin_amdgcn_exp2f(x)
#else
#define EXP2(x) exp2f(x)
#endif

__device__ __forceinline__ void gll16(const void* g, const void* l) {
  __builtin_amdgcn_global_load_lds(
      (const __attribute__((address_space(1))) unsigned int*)g,
      (__attribute__((address_space(3))) unsigned int*)l, 16, 0, 0);
}

__device__ __forceinline__ unsigned lds_addr(const void* p) {
  return (unsigned)(size_t)(__attribute__((address_space(3))) const void*)p;
}

// ---------------------------------------------------------------- cvt: 4 weights (y<4), x hi+lo (y==4), Wf hi+lo + qkmax zero (y==5)
// NOTE (R7 lesson): do NOT fuse a lane-row-scattered fp32 gate dot in here — a wave load touching
// 64 scattered 16B segments of Wf is uncoalesced and collapsed cvt to 70us. Gate stays MFMA-based.
__global__ __launch_bounds__(256) void cvt_all_kernel(
    const float* __restrict__ x,
    const float* __restrict__ w0, const float* __restrict__ w1,
    const float* __restrict__ w2, const float* __restrict__ w3,
    const float* __restrict__ wf,
    unsigned short* __restrict__ xo, unsigned short* __restrict__ xlo,
    unsigned short* __restrict__ o0, unsigned short* __restrict__ o1,
    unsigned short* __restrict__ o2, unsigned short* __restrict__ o3,
    unsigned short* __restrict__ wfh, unsigned short* __restrict__ wfl,
    unsigned* __restrict__ qkmaxu) {
  const int y = blockIdx.y;
  if (y < 4) {
    const float* in = (y == 0) ? w0 : (y == 1) ? w1 : (y == 2) ? w2 : w3;
    unsigned short* out = (y == 0) ? o0 : (y == 1) ? o1 : (y == 2) ? o2 : o3;
    const int i = blockIdx.x * 256 + threadIdx.x;  // 262144 items
    f32x4 v = reinterpret_cast<const f32x4*>(in)[i];
    u16x4 o;
#pragma unroll
    for (int e = 0; e < 4; ++e) o[e] = f2bf(v[e]);
    reinterpret_cast<u16x4*>(out)[i] = o;
  } else if (y == 4) {
    const int i0 = blockIdx.x * 256 + threadIdx.x;
#pragma unroll
    for (int e = 0; e < 4; ++e) {
      const int i = i0 + e * 262144;
      f32x4 v = reinterpret_cast<const f32x4*>(x)[i];
      u16x4 h, l;
#pragma unroll
      for (int q = 0; q < 4; ++q) {
        h[q] = f2bf(v[q]);
        const float hf = __builtin_bit_cast(float, (unsigned)h[q] << 16);
        l[q] = f2bf(v[q] - hf);
      }
      reinterpret_cast<u16x4*>(xo)[i] = h;
      reinterpret_cast<u16x4*>(xlo)[i] = l;
    }
  } else {
    if (blockIdx.x < 16) {
      const int i = blockIdx.x * 256 + threadIdx.x;  // 4096 f32x4 = 16K f32
      f32x4 v = reinterpret_cast<const f32x4*>(wf)[i];
      u16x4 h, l;
#pragma unroll
      for (int q = 0; q < 4; ++q) {
        h[q] = f2bf(v[q]);
        const float hf = __builtin_bit_cast(float, (unsigned)h[q] << 16);
        l[q] = f2bf(v[q] - hf);
      }
      reinterpret_cast<u16x4*>(wfh)[i] = h;
      reinterpret_cast<u16x4*>(wfl)[i] = l;
    } else if (blockIdx.x == 16) {
      if (threadIdx.x < 64) qkmaxu[threadIdx.x] = 0u;  // zero-init for atomicMax (workspace is poisoned)
    }
  }
}

// ---------------------------------------------------------------- GEMM C = A @ B^T, 128x128 tile, BK=64 (kept for Wo)
template <bool OUT_BF16>
__global__ __launch_bounds__(256) void gemm3_kernel(
    const unsigned short* __restrict__ A,
    const unsigned short* __restrict__ B0, const unsigned short* __restrict__ B1,
    const unsigned short* __restrict__ B2,
    void* __restrict__ C0, void* __restrict__ C1, void* __restrict__ C2) {
  __shared__ unsigned short Asm[128 * 64];
  __shared__ unsigned short Bsm[128 * 64];
  const int tid = threadIdx.x, wid = tid >> 6, lane = tid & 63;
  const int g = lane >> 4, l16 = lane & 15;
  const int wr = wid >> 1, wc = wid & 1;
  const int mb = blockIdx.y;
  const int nb = blockIdx.x;
  const int which = nb >> 3;
  const int col0 = (nb & 7) * 128;
  const unsigned short* Bp = (which == 0) ? B0 : (which == 1) ? B1 : B2;
  void* Cp = (which == 0) ? C0 : (which == 1) ? C1 : C2;

  f32x4 acc[4][4] = {};

  for (int k0 = 0; k0 < EMBED; k0 += 64) {
    __syncthreads();
#pragma unroll
    for (int q = 0; q < 4; ++q) {
      const int base = (wid * 4 + q) * 1024;
      const int off = base + lane * 16;
      const int row = off >> 7;
      const int colel = (off & 127) >> 1;
      gll16(A + (size_t)(mb * 128 + row) * EMBED + k0 + colel, (const char*)Asm + base);
      gll16(Bp + (size_t)(col0 + row) * EMBED + k0 + colel, (const char*)Bsm + base);
    }
    __syncthreads();

#pragma unroll
    for (int kc = 0; kc < 2; ++kc) {
      short8 am[4], bm[4];
#pragma unroll
      for (int mi = 0; mi < 4; ++mi)
        am[mi] = *reinterpret_cast<const short8*>(&Asm[(wr * 64 + mi * 16 + l16) * 64 + kc * 32 + g * 8]);
#pragma unroll
      for (int ni = 0; ni < 4; ++ni)
        bm[ni] = *reinterpret_cast<const short8*>(&Bsm[(wc * 64 + ni * 16 + l16) * 64 + kc * 32 + g * 8]);
#pragma unroll
      for (int mi = 0; mi < 4; ++mi)
#pragma unroll
        for (int ni = 0; ni < 4; ++ni)
          acc[mi][ni] = __builtin_amdgcn_mfma_f32_16x16x32_bf16(am[mi], bm[ni], acc[mi][ni], 0, 0, 0);
    }
  }

#pragma unroll
  for (int mi = 0; mi < 4; ++mi)
#pragma unroll
    for (int ni = 0; ni < 4; ++ni)
#pragma unroll
      for (int r = 0; r < 4; ++r) {
        const int m = mb * 128 + wr * 64 + mi * 16 + g * 4 + r;
        const int n = col0 + wc * 64 + ni * 16 + l16;
        if (OUT_BF16)
          ((unsigned short*)Cp)[(size_t)m * EMBED + n] = f2bf(acc[mi][ni][r]);
        else
          ((float*)Cp)[(size_t)m * EMBED + n] = acc[mi][ni][r];
      }
}

// ---------------------------------------------------------------- 256x256 8-phase GEMM C = A @ B^T (QKV path)
// 8 waves (2M x 4N), BK=64, 2 K-tiles per iteration, counted vmcnt(4) at phases 4/8,
// LDS XOR-swizzle byte ^= (row&7)<<4 (write side: pre-swizzled gll16 source; read side: swizzled ds_read addr).
// LDS: [dbuf][A=0/B=1][half][128*64] bf16 = 128 KiB, double-buffered by K-tile parity.
// XCD swizzle (R7 A/B): xcd = linear_id & 7 (matches HW round-robin); each XCD owns 2 mb x 12 nb
// -> A-panels (1MB) L2-resident per XCD.
// FUSED maxabs: wave's output cols span ONE head; wave-reduce max|bf16(acc)|, atomicMax qkmaxu.
#define BAR() asm volatile("s_barrier" ::: "memory")
#define LGKM0()                                              \
  do {                                                       \
    asm volatile("s_waitcnt lgkmcnt(0)" ::: "memory");       \
    __builtin_amdgcn_sched_barrier(0);                       \
  } while (0)
#define VM(n_) asm volatile("s_waitcnt vmcnt(" #n_ ")" ::: "memory")

template <bool OUT_BF16>
__global__ __launch_bounds__(512, 2) void gemm256_kernel(
    const unsigned short* __restrict__ A,
    const unsigned short* __restrict__ B0, const unsigned short* __restrict__ B1,
    const unsigned short* __restrict__ B2,
    void* __restrict__ C0, void* __restrict__ C1, void* __restrict__ C2,
    unsigned* __restrict__ qkmaxu) {
  __shared__ unsigned short sm[2][2][2][8192];  // [dbuf][AB][half][row*64+col] : 128 KiB
  const int tid = threadIdx.x, wid = tid >> 6, lane = tid & 63;
  const int g = lane >> 4, l16 = lane & 15;
  const int wr = wid >> 2, wcol = wid & 3;  // wave tile: rows wr*128.. , cols wcol*64..
  // XCD-aware bijective swizzle of the 192-block grid (8 XCDs x 24 blocks = 2 mb x 12 nb each)
  const int id = blockIdx.y * 12 + blockIdx.x;
  const int xcd = id & 7, loc = id >> 3;  // loc in [0,24)
  const int mb = (xcd << 1) + (loc >= 12 ? 1 : 0);
  const int nb = (loc >= 12) ? (loc - 12) : loc;
  const int which = nb >> 2;
  const int col0 = (nb & 3) * 256;
  const unsigned short* Bp = (which == 0) ? B0 : (which == 1) ? B1 : B2;
  void* Cp = (which == 0) ? C0 : (which == 1) ? C1 : C2;

  // ---- staging invariants (pre-swizzled global source, linear LDS dest) ----
  const int lane8 = lane & 7, laneHi = lane >> 3;
  const int colel = (lane8 ^ laneHi) * 8;  // source col element (inverse swizzle; row&7 == laneHi)
  int soff[2];
#pragma unroll
  for (int q = 0; q < 2; ++q)
    soff[q] = (q * 64 + wid * 8 + laneHi) * EMBED + colel;  // element offset within a half-panel
  const unsigned short* Ag = A + (size_t)(mb * 256) * EMBED;
  const unsigned short* Bg = Bp + (size_t)col0 * EMBED;

  // ---- ds_read invariants (swizzled column offsets; row&7 == l16&7 for all frag rows) ----
  const int sw = (l16 & 7) << 4;
  const int cs0 = (0 | (g * 16)) ^ sw;   // kc=0
  const int cs1 = (64 | (g * 16)) ^ sw;  // kc=1
  const char* smB = (const char*)sm;
  const int aBase = wr * 16384 + l16 * 128;
  const int bBase = 32768 + (wcol >> 1) * 16384 + (wcol & 1) * 8192 + l16 * 128;

#define STG(buf_, ab_, half_, gsrc_, t_)                                               \
  do {                                                                                 \
    const unsigned short* gp_ = (gsrc_) + (size_t)(half_) * (128 * EMBED) + (t_) * 64; \
    char* lp_ = (char*)sm + (buf_) * 65536 + (ab_) * 32768 + (half_) * 16384 + wid * 1024; \
    gll16(gp_ + soff[0], lp_);                                                         \
    gll16(gp_ + soff[1], lp_ + 8192);                                                  \
  } while (0)

#define RD_A(buf_, row_, kc_) \
  (*reinterpret_cast<const short8*>(smB + (buf_) * 65536 + aBase + (row_) * 2048 + ((kc_) ? cs1 : cs0)))
#define RD_B(buf_, row_, kc_) \
  (*reinterpret_cast<const short8*>(smB + (buf_) * 65536 + bBase + (row_) * 2048 + ((kc_) ? cs1 : cs0)))

#define QUAD(mg_, ng_)                                                                   \
  do {                                                                                   \
    __builtin_amdgcn_s_setprio(1);                                                       \
    _Pragma("unroll") for (int kc_ = 0; kc_ < 2; ++kc_)                                  \
      _Pragma("unroll") for (int mi_ = 0; mi_ < 4; ++mi_)                                \
        _Pragma("unroll") for (int nj_ = 0; nj_ < 2; ++nj_)                              \
          acc[(mg_) * 4 + mi_][(ng_) * 2 + nj_] = __builtin_amdgcn_mfma_f32_16x16x32_bf16( \
              fa[mi_][kc_], fb[(ng_) * 2 + nj_][kc_], acc[(mg_) * 4 + mi_][(ng_) * 2 + nj_], 0, 0, 0); \
    __builtin_amdgcn_s_setprio(0);                                                       \
  } while (0)

  // 4 phases of one K-tile: ph1 {12 ds_reads, stage, Q(0,0)}, ph2 {4, stage, Q(0,1)},
  // ph3 {8, stage, Q(1,0)}, ph4 {stage+vmcnt, Q(1,1)}
#define KTILE4(BUF_, STG_P1, STG_P2, STG_P3, STG_P4_VM)                                  \
  do {                                                                                   \
    _Pragma("unroll") for (int mi_ = 0; mi_ < 4; ++mi_) {                                \
      fa[mi_][0] = RD_A(BUF_, mi_, 0);                                                   \
      fa[mi_][1] = RD_A(BUF_, mi_, 1);                                                   \
    }                                                                                    \
    _Pragma("unroll") for (int ni_ = 0; ni_ < 2; ++ni_) {                                \
      fb[ni_][0] = RD_B(BUF_, ni_, 0);                                                   \
      fb[ni_][1] = RD_B(BUF_, ni_, 1);                                                   \
    }                                                                                    \
    STG_P1;                                                                              \
    asm volatile("s_waitcnt lgkmcnt(8)" ::: "memory");                                   \
    BAR();                                                                               \
    LGKM0();                                                                             \
    QUAD(0, 0);                                                                          \
    BAR();                                                                               \
    _Pragma("unroll") for (int ni_ = 0; ni_ < 2; ++ni_) {                                \
      fb[2 + ni_][0] = RD_B(BUF_, 2 + ni_, 0);                                           \
      fb[2 + ni_][1] = RD_B(BUF_, 2 + ni_, 1);                                           \
    }                                                                                    \
    STG_P2;                                                                              \
    BAR();                                                                               \
    LGKM0();                                                                             \
    QUAD(0, 1);                                                                          \
    BAR();                                                                               \
    _Pragma("unroll") for (int mi_ = 0; mi_ < 4; ++mi_) {                                \
      fa[mi_][0] = RD_A(BUF_, 4 + mi_, 0);                                               \
      fa[mi_][1] = RD_A(BUF_, 4 + mi_, 1);                                               \
    }                                                                                    \
    STG_P3;                                                                              \
    BAR();                                                                               \
    LGKM0();                                                                             \
    QUAD(1, 0);                                                                          \
    BAR();                                                                               \
    STG_P4_VM;                                                                           \
    BAR();                                                                               \
    QUAD(1, 1);                                                                          \
    BAR();                                                                               \
  } while (0)

  short8 fa[4][2], fb[4][2];
  f32x4 acc[8][4] = {};

  // ---- prologue: tile0 fully (A0,B0,A1,B1) + tile1 B-halves; wait tile0, keep 2 halves in flight ----
  STG(0, 0, 0, Ag, 0);
  STG(0, 1, 0, Bg, 0);
  STG(0, 0, 1, Ag, 0);
  STG(0, 1, 1, Bg, 0);
  STG(1, 1, 0, Bg, 1);
  STG(1, 1, 1, Bg, 1);
  VM(4);
  BAR();

  // ---- main loop: 16 K-tiles, 2 per iteration (buf0 then buf1), 8 phases ----
  for (int it = 0; it < 8; ++it) {
    const int t1 = 2 * it + 1, t2 = 2 * it + 2, t3 = 2 * it + 3;
    const bool nl = (it < 7);
    // K-tile 2i (buf0); stage t1's A-halves (buf1) then t2's B-halves (buf0, released after ph2)
    KTILE4(0,
           STG(1, 0, 0, Ag, t1),
           STG(1, 0, 1, Ag, t1),
           if (nl) STG(0, 1, 0, Bg, t2),
           if (nl) { STG(0, 1, 1, Bg, t2); VM(4); } else VM(0));
    // K-tile 2i+1 (buf1); stage t2's A-halves (buf0, released after ph3) then t3's B-halves (buf1)
    KTILE4(1,
           if (nl) STG(0, 0, 0, Ag, t2),
           if (nl) STG(0, 0, 1, Ag, t2),
           if (nl) STG(1, 1, 0, Bg, t3),
           if (nl) { STG(1, 1, 1, Bg, t3); VM(4); });
  }

  // ---- epilogue (+ fused maxabs for Q/K tensors) ----
  unsigned mxv = 0;
#pragma unroll
  for (int mi = 0; mi < 8; ++mi)
#pragma unroll
    for (int ni = 0; ni < 4; ++ni)
#pragma unroll
      for (int r = 0; r < 4; ++r) {
        const int m = mb * 256 + wr * 128 + mi * 16 + g * 4 + r;
        const int n = col0 + wcol * 64 + ni * 16 + l16;
        if (OUT_BF16) {
          const unsigned short bv = f2bf(acc[mi][ni][r]);
          ((unsigned short*)Cp)[(size_t)m * EMBED + n] = bv;
          const unsigned a = bv & 0x7fffu;
          mxv = a > mxv ? a : mxv;
        } else {
          ((float*)Cp)[(size_t)m * EMBED + n] = acc[mi][ni][r];
        }
      }
  if (OUT_BF16 && which < 2) {
#pragma unroll
    for (int mm = 1; mm < 64; mm <<= 1) {
      const unsigned o = __shfl_xor(mxv, mm);
      mxv = o > mxv ? o : mxv;
    }
    if (lane == 0) {
      const int bbat = (mb >= 8) ? 1 : 0;
      const int head = (nb & 3) * 4 + wcol;
      const int idx = which * 32 + bbat * 16 + head;
      atomicMax(&qkmaxu[idx], mxv << 16);  // positive-float bits: uint max == float max
    }
  }
#undef STG
#undef RD_A
#undef RD_B
#undef QUAD
#undef KTILE4
}
#undef BAR
#undef LGKM0
#undef VM

// ---------------------------------------------------------------- gate via MFMA, split-bf16 compensated, SPLIT-K:
// s = x_hi@Wf_hi^T + x_hi@Wf_lo^T + x_lo@Wf_hi^T  (fp32 MFMA accum; dropped lo*lo ~ 2^-18)
// 256 blocks, one 16-row M-tile per BLOCK; wave wid owns K-quarter (256 elems = 8 iters),
// partials reduced via LDS. All 256 CUs stream x -> HBM-BW-bound floor ~3 us.
__global__ __launch_bounds__(256) void gate_kernel(
    const unsigned short* __restrict__ xh, const unsigned short* __restrict__ xl,
    const unsigned short* __restrict__ wh, const unsigned short* __restrict__ wl,
    float* __restrict__ c) {
  __shared__ f32x4 red[4][64];
  const int tid = threadIdx.x, wid = tid >> 6, lane = tid & 63;
  const int g = lane >> 4, l16 = lane & 15;
  const int row0 = blockIdx.x * 16;
  const int k0 = wid * 256;  // this wave's K-quarter
  const unsigned short* xhp = xh + (size_t)(row0 + l16) * EMBED + k0 + g * 8;
  const unsigned short* xlp = xl + (size_t)(row0 + l16) * EMBED + k0 + g * 8;
  const unsigned short* whp = wh + (size_t)l16 * EMBED + k0 + g * 8;
  const unsigned short* wlp = wl + (size_t)l16 * EMBED + k0 + g * 8;
  f32x4 acc = {};
#pragma unroll
  for (int k = 0; k < 8; ++k) {
    const short8 ah = *reinterpret_cast<const short8*>(xhp + k * 32);
    const short8 al = *reinterpret_cast<const short8*>(xlp + k * 32);
    const short8 bh = *reinterpret_cast<const short8*>(whp + k * 32);
    const short8 bl = *reinterpret_cast<const short8*>(wlp + k * 32);
    acc = __builtin_amdgcn_mfma_f32_16x16x32_bf16(ah, bh, acc, 0, 0, 0);
    acc = __builtin_amdgcn_mfma_f32_16x16x32_bf16(ah, bl, acc, 0, 0, 0);
    acc = __builtin_amdgcn_mfma_f32_16x16x32_bf16(al, bh, acc, 0, 0, 0);
  }
  red[wid][lane] = acc;
  __syncthreads();
  if (wid == 0) {
    const f32x4 a = red[0][lane] + red[1][lane] + red[2][lane] + red[3][lane];
    // C layout: row = g*4 + r (within tile), col = l16 = head
#pragma unroll
    for (int r = 0; r < 4; ++r) {
      const float s = a[r];
      const float ls = (fminf(s, 0.f) - log1pf(__expf(-fabsf(s)))) * LOG2E;
      const int n = row0 + g * 4 + r;
      const int b = n >> 11, nn = n & (SEQ - 1);
      c[(size_t)(b * NHEAD + l16) * SEQ + nn] = ls;
    }
  }
}

// ---------------------------------------------------------------- cumsum per (b,h)
__global__ void cumsum_kernel(float* __restrict__ c) {
  const int bh = blockIdx.x;
  const int lane = threadIdx.x;  // 64
  float* p = c + (size_t)bh * SEQ;
  f32x4 vv[8];
  f32x4* vp = reinterpret_cast<f32x4*>(p + lane * 32);
#pragma unroll
  for (int q = 0; q < 8; ++q) vv[q] = vp[q];
  float run = 0.f;
#pragma unroll
  for (int q = 0; q < 8; ++q)
#pragma unroll
    for (int e = 0; e < 4; ++e) { run += vv[q][e]; vv[q][e] = run; }
  float s = run;
#pragma unroll
  for (int off = 1; off < 64; off <<= 1) {
    float u = __shfl_up(s, off);
    if (lane >= off) s += u;
  }
  const float excl = s - run;
#pragma unroll
  for (int q = 0; q < 8; ++q)
#pragma unroll
    for (int e = 0; e < 4; ++e) vv[q][e] += excl;
#pragma unroll
  for (int q = 0; q < 8; ++q) vp[q] = vv[q];
}

// ---------------------------------------------------------------- flash attention, swapped-QK^T, XCD-clustered,
// DECAY-SKIP: tile t is processed only if its rigorous upper bound can matter:
//   contribution(t)/l_ <= 2^( c2[i_min]-c2[t_end] + 2U + 6 ),  U = 64*|q|inf*|k|inf*0.125*LOG2E
// Skip when < 2^-35 (threshold -41-2U). c2 monotone decreasing => single backward scan for t_start.
// Typical horizon ~3-4 tiles => ~5 tiles/block, uniform work, no balance tricks needed.
#define NINF (-3.0e38f)
#define SCL (0.125f * LOG2E)
#define BMARG 14.0f

#define TR_READ(dst, addr, OFF) \
  asm volatile("ds_read_b64_tr_b16 %0, %1 offset:" OFF : "=v"(dst) : "v"(addr))

__global__ __launch_bounds__(256) void fa_attn_kernel(
    const unsigned short* __restrict__ Q, const unsigned short* __restrict__ K,
    const unsigned short* __restrict__ V, const float* __restrict__ C,
    const float* __restrict__ qkmax, unsigned short* __restrict__ O) {
  __shared__ unsigned short Ksm[2][4096];  // 8KB each: [64 j][64 dh], rows XOR-swizzled
  __shared__ unsigned short Vsm[2][4096];  // 8KB each: [4 dblk][64 j][16 d] subtiled
  const int p = blockIdx.x;                 // 0..1023
  const int xcd = p & 7, s2 = p >> 3;       // 128 blocks per XCD
  const int hb = xcd * 4 + (s2 >> 5);       // (b,h) pair index (4 per XCD -> 2MB L2 set)
  const int qb = s2 & 31;
  const int hh = hb & 15, bb = hb >> 4;
  const int tid = threadIdx.x, wid = tid >> 6, lane = tid & 63;
  const int g = lane >> 4, l16 = lane & 15;
  const int i_base = qb * 64 + wid * 16;

  const float* cptr = C + (size_t)(bb * NHEAD + hh) * SEQ;

  // staging source offsets (elements, relative to tile origin), per lane
  int kOff[2], vOff[2];
#pragma unroll
  for (int qq = 0; qq < 2; ++qq) {
    const int q = wid * 2 + qq;
    {  // K: linear LDS pos pl = q*1024 + lane*16 -> row = pl>>7, swizzled source col
      const int row = q * 8 + (lane >> 3);
      const int colel = ((lane & 7) ^ (lane >> 3)) * 8;
      kOff[qq] = row * EMBED + colel;
    }
    {  // V: subtiled [dblk][j][16]
      const int dblk = q >> 1;
      const int j = (q & 1) * 32 + (lane >> 1);
      const int dlow = (lane & 1) * 8;
      vOff[qq] = j * EMBED + dblk * 16 + dlow;
    }
  }
  const unsigned short* Kbase = K + (size_t)bb * SEQ * EMBED + hh * HD;
  const unsigned short* Vbase = V + (size_t)bb * SEQ * EMBED + hh * HD;

  // K LDS read offsets (bytes), loop-invariant
  const int swz = (l16 & 7) << 4;
  const int koffB0 = ((0) | (g * 16)) ^ swz;
  const int koffB1 = ((64) | (g * 16)) ^ swz;
  const int krowB = l16 * 128;

#define STAGE(bufidx, tt)                                                              \
  do {                                                                                 \
    const unsigned short* kb_ = Kbase + (size_t)(tt) * 64 * EMBED;                     \
    const unsigned short* vb_ = Vbase + (size_t)(tt) * 64 * EMBED;                     \
    _Pragma("unroll") for (int qq = 0; qq < 2; ++qq) {                                 \
      gll16(kb_ + kOff[qq], (const char*)&Ksm[bufidx][0] + (wid * 2 + qq) * 1024);     \
      gll16(vb_ + vOff[qq], (const char*)&Vsm[bufidx][0] + (wid * 2 + qq) * 1024);     \
    }                                                                                  \
  } while (0)

  // Q B-fragments (col=i=l16, k=g*8+e), hoisted
  short8 qf0, qf1;
  {
    const unsigned short* qp = Q + (size_t)(bb * SEQ + i_base + l16) * EMBED + hh * HD + g * 8;
    qf0 = *reinterpret_cast<const short8*>(qp);
    qf1 = *reinterpret_cast<const short8*>(qp + 32);
  }
  const float c2i = cptr[i_base + l16];  // log2-domain cumsum at this lane's row i

  // decay-skip horizon: tile t alive iff c2[i_min] - c2[t*64+63] >= thr
  int t_start = qb;
  {
    const float qm = qkmax[hb];
    const float km = qkmax[32 + hb];
    const float thr = -41.f - 23.0832f * qm * km;  // -41 - 2U, U = 64*0.125*LOG2E*qm*km
    const float c2imin = cptr[qb * 64];
    while (t_start > 0 && (c2imin - cptr[t_start * 64 - 1] >= thr)) --t_start;
  }

  // analytic softmax reference: m_t = -c2(tile-end) + BMARG (monotone since c2 decreasing)
  float mc_prev = (t_start == qb) ? c2i : cptr[t_start * 64 + 63];
  float l_ = 0.f;
  f32x4 accd[4] = {};

  STAGE(0, t_start);
  __syncthreads();

  int buf = 0;
  for (int t = t_start; t <= qb; ++t) {
    if (t < qb) STAGE(buf ^ 1, t + 1);  // prefetch; drained by this iter's end barrier
    const int kv0 = t * 64;
    const bool diag = (t == qb);
    const int nj = diag ? (wid + 1) : 4;  // skip fully-masked j-blocks on diagonal

    const float mc_cur = diag ? c2i : cptr[kv0 + 63];
    const float corr = EXP2(mc_cur - mc_prev);  // <= 1; pure function of c2, no reduction
    mc_prev = mc_cur;
    const float mcB = mc_cur - BMARG;

    // S^T = K·Q^T: col=i=l16, row j = jb*16 + g*4 + r. p = 2^(qk*SCL + mcB - c2_j)
    float pf[4][4];
    float lsum = 0.f;
#pragma unroll
    for (int jb = 0; jb < 4; ++jb) {
      if (jb < nj) {
        const char* kbp = (const char*)&Ksm[buf][0] + jb * 2048 + krowB;
        short8 kf0 = *reinterpret_cast<const short8*>(kbp + koffB0);
        short8 kf1 = *reinterpret_cast<const short8*>(kbp + koffB1);
        f32x4 s = {};
        __builtin_amdgcn_s_setprio(1);
        s = __builtin_amdgcn_mfma_f32_16x16x32_bf16(kf0, qf0, s, 0, 0, 0);
        s = __builtin_amdgcn_mfma_f32_16x16x32_bf16(kf1, qf1, s, 0, 0, 0);
        __builtin_amdgcn_s_setprio(0);
        const f32x4 cv = *reinterpret_cast<const f32x4*>(&cptr[kv0 + jb * 16 + g * 4]);
#pragma unroll
        for (int r = 0; r < 4; ++r) {
          float arg = __builtin_fmaf(s[r], SCL, mcB - cv[r]);
          if (diag && jb == wid && (g * 4 + r > l16)) arg = NINF;  // causal mask
          const float pv = EXP2(arg);
          pf[jb][r] = pv;
          lsum += pv;
        }
      } else {
#pragma unroll
        for (int r = 0; r < 4; ++r) pf[jb][r] = 0.f;
      }
    }
    l_ = l_ * corr + lsum;  // lane-local partial (reduced across g at epilogue)
#pragma unroll
    for (int d = 0; d < 4; ++d) accd[d] *= corr;

    // pack P into B-frags via v_cvt_pk_bf16_f32 (k-slot (g,e) -> j = kc*32 + (e>>2)*16 + g*4 + (e&3))
    u32x4 w0, w1;
    w0[0] = cvtpk(pf[0][0], pf[0][1]); w0[1] = cvtpk(pf[0][2], pf[0][3]);
    w0[2] = cvtpk(pf[1][0], pf[1][1]); w0[3] = cvtpk(pf[1][2], pf[1][3]);
    w1[0] = cvtpk(pf[2][0], pf[2][1]); w1[1] = cvtpk(pf[2][2], pf[2][3]);
    w1[2] = cvtpk(pf[3][0], pf[3][1]); w1[3] = cvtpk(pf[3][2], pf[3][3]);
    const short8 pb0 = __builtin_bit_cast(short8, w0);
    const short8 pb1 = __builtin_bit_cast(short8, w1);

    // O^T += V^T · P : A-frags via tr-read (delivers j = jsub*16 + g*4 + r at d = l16)
    const unsigned vb0 = lds_addr(&Vsm[buf][0]) + lane * 8;
#pragma unroll
    for (int db = 0; db < 4; ++db) {
      const unsigned va = vb0 + db * 2048;
      short4v t0, t1, t2, t3;
      TR_READ(t0, va, "0");
      TR_READ(t1, va, "512");
      TR_READ(t2, va, "1024");
      TR_READ(t3, va, "1536");
      asm volatile("s_waitcnt lgkmcnt(0)" ::: "memory");
      __builtin_amdgcn_sched_barrier(0);
      short8 va0, va1;
#pragma unroll
      for (int e = 0; e < 4; ++e) {
        va0[e] = t0[e]; va0[e + 4] = t1[e];
        va1[e] = t2[e]; va1[e + 4] = t3[e];
      }
      __builtin_amdgcn_s_setprio(1);
      accd[db] = __builtin_amdgcn_mfma_f32_16x16x32_bf16(va0, pb0, accd[db], 0, 0, 0);
      accd[db] = __builtin_amdgcn_mfma_f32_16x16x32_bf16(va1, pb1, accd[db], 0, 0, 0);
      __builtin_amdgcn_s_setprio(0);
    }
    __syncthreads();  // drains vmcnt (stage t+1 done) + all waves' LDS reads of buf
    buf ^= 1;
  }

  // epilogue: reduce l_ across the 4 g-groups (same i=l16), then store O[i][d]
  l_ += __shfl_xor(l_, 16);
  l_ += __shfl_xor(l_, 32);
  const float inv = 1.0f / l_;
  unsigned short* op = O + (size_t)(bb * SEQ + i_base + l16) * EMBED + hh * HD;
#pragma unroll
  for (int db = 0; db < 4; ++db) {
    u32x2 o;
    o[0] = cvtpk(accd[db][0] * inv, accd[db][1] * inv);
    o[1] = cvtpk(accd[db][2] * inv, accd[db][3] * inv);
    *reinterpret_cast<u32x2*>(op + db * 16 + g * 4) = o;
  }
#undef STAGE
}

// ---------------------------------------------------------------- launcher
extern "C" void kernel_launch(void* const* d_in, const int* in_sizes, int n_in,
                              void* d_out, int out_size, void* d_ws, size_t ws_size,
                              hipStream_t stream) {
  const float* x = (const float*)d_in[0];
  const float* Wq = (const float*)d_in[1];
  const float* Wk = (const float*)d_in[2];
  const float* Wv = (const float*)d_in[3];
  const float* Wo = (const float*)d_in[4];
  const float* Wf = (const float*)d_in[5];
  float* out = (float*)d_out;

  char* ws = (char*)d_ws;
  const size_t SZ_X = (size_t)ROWS * EMBED * sizeof(unsigned short);
  const size_t SZ_W = (size_t)EMBED * EMBED * sizeof(unsigned short);
  const size_t SZ_WF = (size_t)NHEAD * EMBED * sizeof(unsigned short);
  unsigned short* xb = (unsigned short*)ws;   ws += SZ_X;
  unsigned short* xlo = (unsigned short*)ws;  ws += SZ_X;
  unsigned short* Wqb = (unsigned short*)ws;  ws += SZ_W;
  unsigned short* Wkb = (unsigned short*)ws;  ws += SZ_W;
  unsigned short* Wvb = (unsigned short*)ws;  ws += SZ_W;
  unsigned short* Wob = (unsigned short*)ws;  ws += SZ_W;
  unsigned short* Wfh = (unsigned short*)ws;  ws += SZ_WF;
  unsigned short* Wfl = (unsigned short*)ws;  ws += SZ_WF;
  unsigned short* Qb = (unsigned short*)ws;   ws += SZ_X;
  unsigned short* Kb = (unsigned short*)ws;   ws += SZ_X;
  unsigned short* Vb = (unsigned short*)ws;   ws += SZ_X;
  unsigned short* attnb = (unsigned short*)ws; ws += SZ_X;
  float* carr = (float*)ws;                   ws += (size_t)BATCH * NHEAD * SEQ * sizeof(float);
  float* qkmax = (float*)ws;                  ws += 64 * sizeof(float);

  cvt_all_kernel<<<dim3(1024, 6), 256, 0, stream>>>(
      x, Wq, Wk, Wv, Wo, Wf, xb, xlo, Wqb, Wkb, Wvb, Wob, Wfh, Wfl,
      (unsigned*)qkmax);

  // gate: split-K MFMA, 256 blocks (one 16-row tile per block, 4 waves over K)
  gate_kernel<<<256, 256, 0, stream>>>(xb, xlo, Wfh, Wfl, carr);

  // QKV projections: 256x256 8-phase kernel, XCD-swizzled grid, fused maxabs
  gemm256_kernel<true><<<dim3(12, 16), 512, 0, stream>>>(
      xb, Wqb, Wkb, Wvb, Qb, Kb, Vb, (unsigned*)qkmax);

  cumsum_kernel<<<BATCH * NHEAD, 64, 0, stream>>>(carr);

  // attention: QBLK=64, 1024 blocks (128 per XCD)
  fa_attn_kernel<<<1024, 256, 0, stream>>>(Qb, Kb, Vb, carr, qkmax, attnb);

  gemm3_kernel<false><<<dim3(8, 32), 256, 0, stream>>>(
      attnb, Wob, Wob, Wob, out, out, out);
}

// Round 9
// 96.274 us; speedup vs baseline: 1.5533x; 1.0579x over previous
//
#include <hip/hip_runtime.h>

// Problem constants
#define EMBED 1024
#define NHEAD 16
#define HD    64
#define SEQ   2048
#define BATCH 2
#define ROWS  (BATCH * SEQ)  // 4096

typedef float f32x4 __attribute__((ext_vector_type(4)));
typedef short short8 __attribute__((ext_vector_type(8)));
typedef short short4v __attribute__((ext_vector_type(4)));
typedef unsigned short u16x4 __attribute__((ext_vector_type(4)));
typedef unsigned short u16x8 __attribute__((ext_vector_type(8)));
typedef unsigned u32x4 __attribute__((ext_vector_type(4)));
typedef unsigned u32x2 __attribute__((ext_vector_type(2)));

#define LOG2E 1.4426950408889634f

__device__ __forceinline__ unsigned short f2bf(float f) {
  unsigned int u = __builtin_bit_cast(unsigned int, f);
  u += 0x7fffu + ((u >> 16) & 1u);  // round-to-nearest-even
  return (unsigned short)(u >> 16);
}

// pack 2 f32 -> 2 bf16 in one u32 (RNE), gfx950
__device__ __forceinline__ unsigned cvtpk(float lo, float hi) {
  unsigned r;
  asm("v_cvt_pk_bf16_f32 %0, %1, %2" : "=v"(r) : "v"(lo), "v"(hi));
  return r;
}

#if __has_builtin(__builtin_amdgcn_exp2f)
#define EXP2(x) __builtin_amdgcn_exp2f(x)
#else
#define EXP2(x) exp2f(x)
#endif

__device__ __forceinline__ void gll16(const void* g, const void* l) {
  __builtin_amdgcn_global_load_lds(
      (const __attribute__((address_space(1))) unsigned int*)g,
      (__attribute__((address_space(3))) unsigned int*)l, 16, 0, 0);
}

__device__ __forceinline__ unsigned lds_addr(const void* p) {
  return (unsigned)(size_t)(__attribute__((address_space(3))) const void*)p;
}

// ---------------------------------------------------------------- cvt: 4 weights (y<4), x hi+lo (y==4), Wf hi+lo + qkmax zero (y==5)
// NOTE (R7 lesson): do NOT fuse a lane-row-scattered fp32 gate dot in here — a wave load touching
// 64 scattered 16B segments of Wf is uncoalesced and collapsed cvt to 70us. Gate stays MFMA-based.
__global__ __launch_bounds__(256) void cvt_all_kernel(
    const float* __restrict__ x,
    const float* __restrict__ w0, const float* __restrict__ w1,
    const float* __restrict__ w2, const float* __restrict__ w3,
    const float* __restrict__ wf,
    unsigned short* __restrict__ xo, unsigned short* __restrict__ xlo,
    unsigned short* __restrict__ o0, unsigned short* __restrict__ o1,
    unsigned short* __restrict__ o2, unsigned short* __restrict__ o3,
    unsigned short* __restrict__ wfh, unsigned short* __restrict__ wfl,
    unsigned* __restrict__ qkmaxu) {
  const int y = blockIdx.y;
  if (y < 4) {
    const float* in = (y == 0) ? w0 : (y == 1) ? w1 : (y == 2) ? w2 : w3;
    unsigned short* out = (y == 0) ? o0 : (y == 1) ? o1 : (y == 2) ? o2 : o3;
    const int i = blockIdx.x * 256 + threadIdx.x;  // 262144 items
    f32x4 v = reinterpret_cast<const f32x4*>(in)[i];
    u16x4 o;
#pragma unroll
    for (int e = 0; e < 4; ++e) o[e] = f2bf(v[e]);
    reinterpret_cast<u16x4*>(out)[i] = o;
  } else if (y == 4) {
    const int i0 = blockIdx.x * 256 + threadIdx.x;
#pragma unroll
    for (int e = 0; e < 4; ++e) {
      const int i = i0 + e * 262144;
      f32x4 v = reinterpret_cast<const f32x4*>(x)[i];
      u16x4 h, l;
#pragma unroll
      for (int q = 0; q < 4; ++q) {
        h[q] = f2bf(v[q]);
        const float hf = __builtin_bit_cast(float, (unsigned)h[q] << 16);
        l[q] = f2bf(v[q] - hf);
      }
      reinterpret_cast<u16x4*>(xo)[i] = h;
      reinterpret_cast<u16x4*>(xlo)[i] = l;
    }
  } else {
    if (blockIdx.x < 16) {
      const int i = blockIdx.x * 256 + threadIdx.x;  // 4096 f32x4 = 16K f32
      f32x4 v = reinterpret_cast<const f32x4*>(wf)[i];
      u16x4 h, l;
#pragma unroll
      for (int q = 0; q < 4; ++q) {
        h[q] = f2bf(v[q]);
        const float hf = __builtin_bit_cast(float, (unsigned)h[q] << 16);
        l[q] = f2bf(v[q] - hf);
      }
      reinterpret_cast<u16x4*>(wfh)[i] = h;
      reinterpret_cast<u16x4*>(wfl)[i] = l;
    } else if (blockIdx.x == 16) {
      if (threadIdx.x < 64) qkmaxu[threadIdx.x] = 0u;  // zero-init for atomicMax (workspace is poisoned)
    }
  }
}

// ---------------------------------------------------------------- Wo GEMM C = A @ B^T, 64x128 tile, BK=64, fp32 out
// R8 theory: old 128x128 grid was 256 blocks = exactly 1 block/CU -> no cross-block overlap of the
// 2-phase stage/compute loop (m102: occupancy is THE lever for this structure, 320->833 TF at 1->4 /CU).
// 64x128 tile: LDS 24KB, grid 8x64 = 512 blocks = 2/CU. Same K-order per output -> bit-identical result.
__global__ __launch_bounds__(256) void gemm_wo_kernel(
    const unsigned short* __restrict__ A, const unsigned short* __restrict__ B,
    float* __restrict__ C) {
  __shared__ unsigned short Asm[64 * 64];
  __shared__ unsigned short Bsm[128 * 64];
  const int tid = threadIdx.x, wid = tid >> 6, lane = tid & 63;
  const int g = lane >> 4, l16 = lane & 15;
  const int wr = wid >> 1, wc = wid & 1;  // wave tile: rows wr*32, cols wc*64
  const int mb = blockIdx.y;              // 64-row tiles (64 of them)
  const int nb = blockIdx.x;              // 128-col tiles (8 of them)

  f32x4 acc[2][4] = {};

  for (int k0 = 0; k0 < EMBED; k0 += 64) {
    __syncthreads();
    // A: 64x64 bf16 = 8KB (2 wave-issues per wave)
#pragma unroll
    for (int q = 0; q < 2; ++q) {
      const int base = (wid * 2 + q) * 1024;
      const int off = base + lane * 16;
      const int row = off >> 7;
      const int colel = (off & 127) >> 1;
      gll16(A + (size_t)(mb * 64 + row) * EMBED + k0 + colel, (const char*)Asm + base);
    }
    // B: 128x64 bf16 = 16KB (4 wave-issues per wave)
#pragma unroll
    for (int q = 0; q < 4; ++q) {
      const int base = (wid * 4 + q) * 1024;
      const int off = base + lane * 16;
      const int row = off >> 7;
      const int colel = (off & 127) >> 1;
      gll16(B + (size_t)(nb * 128 + row) * EMBED + k0 + colel, (const char*)Bsm + base);
    }
    __syncthreads();

#pragma unroll
    for (int kc = 0; kc < 2; ++kc) {
      short8 am[2], bm[4];
#pragma unroll
      for (int mi = 0; mi < 2; ++mi)
        am[mi] = *reinterpret_cast<const short8*>(&Asm[(wr * 32 + mi * 16 + l16) * 64 + kc * 32 + g * 8]);
#pragma unroll
      for (int ni = 0; ni < 4; ++ni)
        bm[ni] = *reinterpret_cast<const short8*>(&Bsm[(wc * 64 + ni * 16 + l16) * 64 + kc * 32 + g * 8]);
#pragma unroll
      for (int mi = 0; mi < 2; ++mi)
#pragma unroll
        for (int ni = 0; ni < 4; ++ni)
          acc[mi][ni] = __builtin_amdgcn_mfma_f32_16x16x32_bf16(am[mi], bm[ni], acc[mi][ni], 0, 0, 0);
    }
  }

#pragma unroll
  for (int mi = 0; mi < 2; ++mi)
#pragma unroll
    for (int ni = 0; ni < 4; ++ni)
#pragma unroll
      for (int r = 0; r < 4; ++r) {
        const int m = mb * 64 + wr * 32 + mi * 16 + g * 4 + r;
        const int n = nb * 128 + wc * 64 + ni * 16 + l16;
        C[(size_t)m * EMBED + n] = acc[mi][ni][r];
      }
}

// ---------------------------------------------------------------- 256x256 8-phase GEMM C = A @ B^T (QKV path)
// 8 waves (2M x 4N), BK=64, 2 K-tiles per iteration, counted vmcnt(4) at phases 4/8,
// LDS XOR-swizzle byte ^= (row&7)<<4 (write side: pre-swizzled gll16 source; read side: swizzled ds_read addr).
// LDS: [dbuf][A=0/B=1][half][128*64] bf16 = 128 KiB, double-buffered by K-tile parity.
// (R8 A/B: XCD swizzle was null-to-negative -> plain blockIdx mapping.)
// FUSED maxabs: wave's output cols span ONE head; wave-reduce max|bf16(acc)|, atomicMax qkmaxu.
#define BAR() asm volatile("s_barrier" ::: "memory")
#define LGKM0()                                              \
  do {                                                       \
    asm volatile("s_waitcnt lgkmcnt(0)" ::: "memory");       \
    __builtin_amdgcn_sched_barrier(0);                       \
  } while (0)
#define VM(n_) asm volatile("s_waitcnt vmcnt(" #n_ ")" ::: "memory")

template <bool OUT_BF16>
__global__ __launch_bounds__(512, 2) void gemm256_kernel(
    const unsigned short* __restrict__ A,
    const unsigned short* __restrict__ B0, const unsigned short* __restrict__ B1,
    const unsigned short* __restrict__ B2,
    void* __restrict__ C0, void* __restrict__ C1, void* __restrict__ C2,
    unsigned* __restrict__ qkmaxu) {
  __shared__ unsigned short sm[2][2][2][8192];  // [dbuf][AB][half][row*64+col] : 128 KiB
  const int tid = threadIdx.x, wid = tid >> 6, lane = tid & 63;
  const int g = lane >> 4, l16 = lane & 15;
  const int wr = wid >> 2, wcol = wid & 3;  // wave tile: rows wr*128.. , cols wcol*64..
  const int mb = blockIdx.y;
  const int nb = blockIdx.x;  // 0..11 : which = nb>>2, col0 = (nb&3)*256
  const int which = nb >> 2;
  const int col0 = (nb & 3) * 256;
  const unsigned short* Bp = (which == 0) ? B0 : (which == 1) ? B1 : B2;
  void* Cp = (which == 0) ? C0 : (which == 1) ? C1 : C2;

  // ---- staging invariants (pre-swizzled global source, linear LDS dest) ----
  const int lane8 = lane & 7, laneHi = lane >> 3;
  const int colel = (lane8 ^ laneHi) * 8;  // source col element (inverse swizzle; row&7 == laneHi)
  int soff[2];
#pragma unroll
  for (int q = 0; q < 2; ++q)
    soff[q] = (q * 64 + wid * 8 + laneHi) * EMBED + colel;  // element offset within a half-panel
  const unsigned short* Ag = A + (size_t)(mb * 256) * EMBED;
  const unsigned short* Bg = Bp + (size_t)col0 * EMBED;

  // ---- ds_read invariants (swizzled column offsets; row&7 == l16&7 for all frag rows) ----
  const int sw = (l16 & 7) << 4;
  const int cs0 = (0 | (g * 16)) ^ sw;   // kc=0
  const int cs1 = (64 | (g * 16)) ^ sw;  // kc=1
  const char* smB = (const char*)sm;
  const int aBase = wr * 16384 + l16 * 128;
  const int bBase = 32768 + (wcol >> 1) * 16384 + (wcol & 1) * 8192 + l16 * 128;

#define STG(buf_, ab_, half_, gsrc_, t_)                                               \
  do {                                                                                 \
    const unsigned short* gp_ = (gsrc_) + (size_t)(half_) * (128 * EMBED) + (t_) * 64; \
    char* lp_ = (char*)sm + (buf_) * 65536 + (ab_) * 32768 + (half_) * 16384 + wid * 1024; \
    gll16(gp_ + soff[0], lp_);                                                         \
    gll16(gp_ + soff[1], lp_ + 8192);                                                  \
  } while (0)

#define RD_A(buf_, row_, kc_) \
  (*reinterpret_cast<const short8*>(smB + (buf_) * 65536 + aBase + (row_) * 2048 + ((kc_) ? cs1 : cs0)))
#define RD_B(buf_, row_, kc_) \
  (*reinterpret_cast<const short8*>(smB + (buf_) * 65536 + bBase + (row_) * 2048 + ((kc_) ? cs1 : cs0)))

#define QUAD(mg_, ng_)                                                                   \
  do {                                                                                   \
    __builtin_amdgcn_s_setprio(1);                                                       \
    _Pragma("unroll") for (int kc_ = 0; kc_ < 2; ++kc_)                                  \
      _Pragma("unroll") for (int mi_ = 0; mi_ < 4; ++mi_)                                \
        _Pragma("unroll") for (int nj_ = 0; nj_ < 2; ++nj_)                              \
          acc[(mg_) * 4 + mi_][(ng_) * 2 + nj_] = __builtin_amdgcn_mfma_f32_16x16x32_bf16( \
              fa[mi_][kc_], fb[(ng_) * 2 + nj_][kc_], acc[(mg_) * 4 + mi_][(ng_) * 2 + nj_], 0, 0, 0); \
    __builtin_amdgcn_s_setprio(0);                                                       \
  } while (0)

  // 4 phases of one K-tile: ph1 {12 ds_reads, stage, Q(0,0)}, ph2 {4, stage, Q(0,1)},
  // ph3 {8, stage, Q(1,0)}, ph4 {stage+vmcnt, Q(1,1)}
#define KTILE4(BUF_, STG_P1, STG_P2, STG_P3, STG_P4_VM)                                  \
  do {                                                                                   \
    _Pragma("unroll") for (int mi_ = 0; mi_ < 4; ++mi_) {                                \
      fa[mi_][0] = RD_A(BUF_, mi_, 0);                                                   \
      fa[mi_][1] = RD_A(BUF_, mi_, 1);                                                   \
    }                                                                                    \
    _Pragma("unroll") for (int ni_ = 0; ni_ < 2; ++ni_) {                                \
      fb[ni_][0] = RD_B(BUF_, ni_, 0);                                                   \
      fb[ni_][1] = RD_B(BUF_, ni_, 1);                                                   \
    }                                                                                    \
    STG_P1;                                                                              \
    asm volatile("s_waitcnt lgkmcnt(8)" ::: "memory");                                   \
    BAR();                                                                               \
    LGKM0();                                                                             \
    QUAD(0, 0);                                                                          \
    BAR();                                                                               \
    _Pragma("unroll") for (int ni_ = 0; ni_ < 2; ++ni_) {                                \
      fb[2 + ni_][0] = RD_B(BUF_, 2 + ni_, 0);                                           \
      fb[2 + ni_][1] = RD_B(BUF_, 2 + ni_, 1);                                           \
    }                                                                                    \
    STG_P2;                                                                              \
    BAR();                                                                               \
    LGKM0();                                                                             \
    QUAD(0, 1);                                                                          \
    BAR();                                                                               \
    _Pragma("unroll") for (int mi_ = 0; mi_ < 4; ++mi_) {                                \
      fa[mi_][0] = RD_A(BUF_, 4 + mi_, 0);                                               \
      fa[mi_][1] = RD_A(BUF_, 4 + mi_, 1);                                               \
    }                                                                                    \
    STG_P3;                                                                              \
    BAR();                                                                               \
    LGKM0();                                                                             \
    QUAD(1, 0);                                                                          \
    BAR();                                                                               \
    STG_P4_VM;                                                                           \
    BAR();                                                                               \
    QUAD(1, 1);                                                                          \
    BAR();                                                                               \
  } while (0)

  short8 fa[4][2], fb[4][2];
  f32x4 acc[8][4] = {};

  // ---- prologue: tile0 fully (A0,B0,A1,B1) + tile1 B-halves; wait tile0, keep 2 halves in flight ----
  STG(0, 0, 0, Ag, 0);
  STG(0, 1, 0, Bg, 0);
  STG(0, 0, 1, Ag, 0);
  STG(0, 1, 1, Bg, 0);
  STG(1, 1, 0, Bg, 1);
  STG(1, 1, 1, Bg, 1);
  VM(4);
  BAR();

  // ---- main loop: 16 K-tiles, 2 per iteration (buf0 then buf1), 8 phases ----
  for (int it = 0; it < 8; ++it) {
    const int t1 = 2 * it + 1, t2 = 2 * it + 2, t3 = 2 * it + 3;
    const bool nl = (it < 7);
    // K-tile 2i (buf0); stage t1's A-halves (buf1) then t2's B-halves (buf0, released after ph2)
    KTILE4(0,
           STG(1, 0, 0, Ag, t1),
           STG(1, 0, 1, Ag, t1),
           if (nl) STG(0, 1, 0, Bg, t2),
           if (nl) { STG(0, 1, 1, Bg, t2); VM(4); } else VM(0));
    // K-tile 2i+1 (buf1); stage t2's A-halves (buf0, released after ph3) then t3's B-halves (buf1)
    KTILE4(1,
           if (nl) STG(0, 0, 0, Ag, t2),
           if (nl) STG(0, 0, 1, Ag, t2),
           if (nl) STG(1, 1, 0, Bg, t3),
           if (nl) { STG(1, 1, 1, Bg, t3); VM(4); });
  }

  // ---- epilogue (+ fused maxabs for Q/K tensors) ----
  unsigned mxv = 0;
#pragma unroll
  for (int mi = 0; mi < 8; ++mi)
#pragma unroll
    for (int ni = 0; ni < 4; ++ni)
#pragma unroll
      for (int r = 0; r < 4; ++r) {
        const int m = mb * 256 + wr * 128 + mi * 16 + g * 4 + r;
        const int n = col0 + wcol * 64 + ni * 16 + l16;
        if (OUT_BF16) {
          const unsigned short bv = f2bf(acc[mi][ni][r]);
          ((unsigned short*)Cp)[(size_t)m * EMBED + n] = bv;
          const unsigned a = bv & 0x7fffu;
          mxv = a > mxv ? a : mxv;
        } else {
          ((float*)Cp)[(size_t)m * EMBED + n] = acc[mi][ni][r];
        }
      }
  if (OUT_BF16 && which < 2) {
#pragma unroll
    for (int mm = 1; mm < 64; mm <<= 1) {
      const unsigned o = __shfl_xor(mxv, mm);
      mxv = o > mxv ? o : mxv;
    }
    if (lane == 0) {
      const int bbat = (mb >= 8) ? 1 : 0;
      const int head = (nb & 3) * 4 + wcol;
      const int idx = which * 32 + bbat * 16 + head;
      atomicMax(&qkmaxu[idx], mxv << 16);  // positive-float bits: uint max == float max
    }
  }
#undef STG
#undef RD_A
#undef RD_B
#undef QUAD
#undef KTILE4
}
#undef BAR
#undef LGKM0
#undef VM

// ---------------------------------------------------------------- gate via MFMA, split-bf16 compensated, SPLIT-K:
// s = x_hi@Wf_hi^T + x_hi@Wf_lo^T + x_lo@Wf_hi^T  (fp32 MFMA accum; dropped lo*lo ~ 2^-18)
// 256 blocks, one 16-row M-tile per BLOCK; wave wid owns K-quarter (256 elems = 8 iters),
// partials reduced via LDS. All 256 CUs stream x -> HBM-BW-bound floor ~3 us.
__global__ __launch_bounds__(256) void gate_kernel(
    const unsigned short* __restrict__ xh, const unsigned short* __restrict__ xl,
    const unsigned short* __restrict__ wh, const unsigned short* __restrict__ wl,
    float* __restrict__ c) {
  __shared__ f32x4 red[4][64];
  const int tid = threadIdx.x, wid = tid >> 6, lane = tid & 63;
  const int g = lane >> 4, l16 = lane & 15;
  const int row0 = blockIdx.x * 16;
  const int k0 = wid * 256;  // this wave's K-quarter
  const unsigned short* xhp = xh + (size_t)(row0 + l16) * EMBED + k0 + g * 8;
  const unsigned short* xlp = xl + (size_t)(row0 + l16) * EMBED + k0 + g * 8;
  const unsigned short* whp = wh + (size_t)l16 * EMBED + k0 + g * 8;
  const unsigned short* wlp = wl + (size_t)l16 * EMBED + k0 + g * 8;
  f32x4 acc = {};
#pragma unroll
  for (int k = 0; k < 8; ++k) {
    const short8 ah = *reinterpret_cast<const short8*>(xhp + k * 32);
    const short8 al = *reinterpret_cast<const short8*>(xlp + k * 32);
    const short8 bh = *reinterpret_cast<const short8*>(whp + k * 32);
    const short8 bl = *reinterpret_cast<const short8*>(wlp + k * 32);
    acc = __builtin_amdgcn_mfma_f32_16x16x32_bf16(ah, bh, acc, 0, 0, 0);
    acc = __builtin_amdgcn_mfma_f32_16x16x32_bf16(ah, bl, acc, 0, 0, 0);
    acc = __builtin_amdgcn_mfma_f32_16x16x32_bf16(al, bh, acc, 0, 0, 0);
  }
  red[wid][lane] = acc;
  __syncthreads();
  if (wid == 0) {
    const f32x4 a = red[0][lane] + red[1][lane] + red[2][lane] + red[3][lane];
    // C layout: row = g*4 + r (within tile), col = l16 = head
#pragma unroll
    for (int r = 0; r < 4; ++r) {
      const float s = a[r];
      const float ls = (fminf(s, 0.f) - log1pf(__expf(-fabsf(s)))) * LOG2E;
      const int n = row0 + g * 4 + r;
      const int b = n >> 11, nn = n & (SEQ - 1);
      c[(size_t)(b * NHEAD + l16) * SEQ + nn] = ls;
    }
  }
}

// ---------------------------------------------------------------- cumsum per (b,h)
__global__ void cumsum_kernel(float* __restrict__ c) {
  const int bh = blockIdx.x;
  const int lane = threadIdx.x;  // 64
  float* p = c + (size_t)bh * SEQ;
  f32x4 vv[8];
  f32x4* vp = reinterpret_cast<f32x4*>(p + lane * 32);
#pragma unroll
  for (int q = 0; q < 8; ++q) vv[q] = vp[q];
  float run = 0.f;
#pragma unroll
  for (int q = 0; q < 8; ++q)
#pragma unroll
    for (int e = 0; e < 4; ++e) { run += vv[q][e]; vv[q][e] = run; }
  float s = run;
#pragma unroll
  for (int off = 1; off < 64; off <<= 1) {
    float u = __shfl_up(s, off);
    if (lane >= off) s += u;
  }
  const float excl = s - run;
#pragma unroll
  for (int q = 0; q < 8; ++q)
#pragma unroll
    for (int e = 0; e < 4; ++e) vv[q][e] += excl;
#pragma unroll
  for (int q = 0; q < 8; ++q) vp[q] = vv[q];
}

// ---------------------------------------------------------------- flash attention, swapped-QK^T, XCD-clustered,
// DECAY-SKIP: tile t is processed only if its rigorous upper bound can matter:
//   contribution(t)/l_ <= 2^( c2[i_min]-c2[t_end] + 2U + 6 ),  U = 64*|q|inf*|k|inf*0.125*LOG2E
// Skip when < 2^-35 (threshold -41-2U). c2 monotone decreasing => single backward scan for t_start.
// Typical horizon ~3-4 tiles => ~5 tiles/block, uniform work, no balance tricks needed.
#define NINF (-3.0e38f)
#define SCL (0.125f * LOG2E)
#define BMARG 14.0f

#define TR_READ(dst, addr, OFF) \
  asm volatile("ds_read_b64_tr_b16 %0, %1 offset:" OFF : "=v"(dst) : "v"(addr))

__global__ __launch_bounds__(256) void fa_attn_kernel(
    const unsigned short* __restrict__ Q, const unsigned short* __restrict__ K,
    const unsigned short* __restrict__ V, const float* __restrict__ C,
    const float* __restrict__ qkmax, unsigned short* __restrict__ O) {
  __shared__ unsigned short Ksm[2][4096];  // 8KB each: [64 j][64 dh], rows XOR-swizzled
  __shared__ unsigned short Vsm[2][4096];  // 8KB each: [4 dblk][64 j][16 d] subtiled
  const int p = blockIdx.x;                 // 0..1023
  const int xcd = p & 7, s2 = p >> 3;       // 128 blocks per XCD
  const int hb = xcd * 4 + (s2 >> 5);       // (b,h) pair index (4 per XCD -> 2MB L2 set)
  const int qb = s2 & 31;
  const int hh = hb & 15, bb = hb >> 4;
  const int tid = threadIdx.x, wid = tid >> 6, lane = tid & 63;
  const int g = lane >> 4, l16 = lane & 15;
  const int i_base = qb * 64 + wid * 16;

  const float* cptr = C + (size_t)(bb * NHEAD + hh) * SEQ;

  // staging source offsets (elements, relative to tile origin), per lane
  int kOff[2], vOff[2];
#pragma unroll
  for (int qq = 0; qq < 2; ++qq) {
    const int q = wid * 2 + qq;
    {  // K: linear LDS pos pl = q*1024 + lane*16 -> row = pl>>7, swizzled source col
      const int row = q * 8 + (lane >> 3);
      const int colel = ((lane & 7) ^ (lane >> 3)) * 8;
      kOff[qq] = row * EMBED + colel;
    }
    {  // V: subtiled [dblk][j][16]
      const int dblk = q >> 1;
      const int j = (q & 1) * 32 + (lane >> 1);
      const int dlow = (lane & 1) * 8;
      vOff[qq] = j * EMBED + dblk * 16 + dlow;
    }
  }
  const unsigned short* Kbase = K + (size_t)bb * SEQ * EMBED + hh * HD;
  const unsigned short* Vbase = V + (size_t)bb * SEQ * EMBED + hh * HD;

  // K LDS read offsets (bytes), loop-invariant
  const int swz = (l16 & 7) << 4;
  const int koffB0 = ((0) | (g * 16)) ^ swz;
  const int koffB1 = ((64) | (g * 16)) ^ swz;
  const int krowB = l16 * 128;

#define STAGE(bufidx, tt)                                                              \
  do {                                                                                 \
    const unsigned short* kb_ = Kbase + (size_t)(tt) * 64 * EMBED;                     \
    const unsigned short* vb_ = Vbase + (size_t)(tt) * 64 * EMBED;                     \
    _Pragma("unroll") for (int qq = 0; qq < 2; ++qq) {                                 \
      gll16(kb_ + kOff[qq], (const char*)&Ksm[bufidx][0] + (wid * 2 + qq) * 1024);     \
      gll16(vb_ + vOff[qq], (const char*)&Vsm[bufidx][0] + (wid * 2 + qq) * 1024);     \
    }                                                                                  \
  } while (0)

  // Q B-fragments (col=i=l16, k=g*8+e), hoisted
  short8 qf0, qf1;
  {
    const unsigned short* qp = Q + (size_t)(bb * SEQ + i_base + l16) * EMBED + hh * HD + g * 8;
    qf0 = *reinterpret_cast<const short8*>(qp);
    qf1 = *reinterpret_cast<const short8*>(qp + 32);
  }
  const float c2i = cptr[i_base + l16];  // log2-domain cumsum at this lane's row i

  // decay-skip horizon: tile t alive iff c2[i_min] - c2[t*64+63] >= thr
  int t_start = qb;
  {
    const float qm = qkmax[hb];
    const float km = qkmax[32 + hb];
    const float thr = -41.f - 23.0832f * qm * km;  // -41 - 2U, U = 64*0.125*LOG2E*qm*km
    const float c2imin = cptr[qb * 64];
    while (t_start > 0 && (c2imin - cptr[t_start * 64 - 1] >= thr)) --t_start;
  }

  // analytic softmax reference: m_t = -c2(tile-end) + BMARG (monotone since c2 decreasing)
  float mc_prev = (t_start == qb) ? c2i : cptr[t_start * 64 + 63];
  float l_ = 0.f;
  f32x4 accd[4] = {};

  STAGE(0, t_start);
  __syncthreads();

  int buf = 0;
  for (int t = t_start; t <= qb; ++t) {
    if (t < qb) STAGE(buf ^ 1, t + 1);  // prefetch; drained by this iter's end barrier
    const int kv0 = t * 64;
    const bool diag = (t == qb);
    const int nj = diag ? (wid + 1) : 4;  // skip fully-masked j-blocks on diagonal

    const float mc_cur = diag ? c2i : cptr[kv0 + 63];
    const float corr = EXP2(mc_cur - mc_prev);  // <= 1; pure function of c2, no reduction
    mc_prev = mc_cur;
    const float mcB = mc_cur - BMARG;

    // S^T = K·Q^T: col=i=l16, row j = jb*16 + g*4 + r. p = 2^(qk*SCL + mcB - c2_j)
    float pf[4][4];
    float lsum = 0.f;
#pragma unroll
    for (int jb = 0; jb < 4; ++jb) {
      if (jb < nj) {
        const char* kbp = (const char*)&Ksm[buf][0] + jb * 2048 + krowB;
        short8 kf0 = *reinterpret_cast<const short8*>(kbp + koffB0);
        short8 kf1 = *reinterpret_cast<const short8*>(kbp + koffB1);
        f32x4 s = {};
        __builtin_amdgcn_s_setprio(1);
        s = __builtin_amdgcn_mfma_f32_16x16x32_bf16(kf0, qf0, s, 0, 0, 0);
        s = __builtin_amdgcn_mfma_f32_16x16x32_bf16(kf1, qf1, s, 0, 0, 0);
        __builtin_amdgcn_s_setprio(0);
        const f32x4 cv = *reinterpret_cast<const f32x4*>(&cptr[kv0 + jb * 16 + g * 4]);
#pragma unroll
        for (int r = 0; r < 4; ++r) {
          float arg = __builtin_fmaf(s[r], SCL, mcB - cv[r]);
          if (diag && jb == wid && (g * 4 + r > l16)) arg = NINF;  // causal mask
          const float pv = EXP2(arg);
          pf[jb][r] = pv;
          lsum += pv;
        }
      } else {
#pragma unroll
        for (int r = 0; r < 4; ++r) pf[jb][r] = 0.f;
      }
    }
    l_ = l_ * corr + lsum;  // lane-local partial (reduced across g at epilogue)
#pragma unroll
    for (int d = 0; d < 4; ++d) accd[d] *= corr;

    // pack P into B-frags via v_cvt_pk_bf16_f32 (k-slot (g,e) -> j = kc*32 + (e>>2)*16 + g*4 + (e&3))
    u32x4 w0, w1;
    w0[0] = cvtpk(pf[0][0], pf[0][1]); w0[1] = cvtpk(pf[0][2], pf[0][3]);
    w0[2] = cvtpk(pf[1][0], pf[1][1]); w0[3] = cvtpk(pf[1][2], pf[1][3]);
    w1[0] = cvtpk(pf[2][0], pf[2][1]); w1[1] = cvtpk(pf[2][2], pf[2][3]);
    w1[2] = cvtpk(pf[3][0], pf[3][1]); w1[3] = cvtpk(pf[3][2], pf[3][3]);
    const short8 pb0 = __builtin_bit_cast(short8, w0);
    const short8 pb1 = __builtin_bit_cast(short8, w1);

    // O^T += V^T · P : A-frags via tr-read (delivers j = jsub*16 + g*4 + r at d = l16)
    const unsigned vb0 = lds_addr(&Vsm[buf][0]) + lane * 8;
#pragma unroll
    for (int db = 0; db < 4; ++db) {
      const unsigned va = vb0 + db * 2048;
      short4v t0, t1, t2, t3;
      TR_READ(t0, va, "0");
      TR_READ(t1, va, "512");
      TR_READ(t2, va, "1024");
      TR_READ(t3, va, "1536");
      asm volatile("s_waitcnt lgkmcnt(0)" ::: "memory");
      __builtin_amdgcn_sched_barrier(0);
      short8 va0, va1;
#pragma unroll
      for (int e = 0; e < 4; ++e) {
        va0[e] = t0[e]; va0[e + 4] = t1[e];
        va1[e] = t2[e]; va1[e + 4] = t3[e];
      }
      __builtin_amdgcn_s_setprio(1);
      accd[db] = __builtin_amdgcn_mfma_f32_16x16x32_bf16(va0, pb0, accd[db], 0, 0, 0);
      accd[db] = __builtin_amdgcn_mfma_f32_16x16x32_bf16(va1, pb1, accd[db], 0, 0, 0);
      __builtin_amdgcn_s_setprio(0);
    }
    __syncthreads();  // drains vmcnt (stage t+1 done) + all waves' LDS reads of buf
    buf ^= 1;
  }

  // epilogue: reduce l_ across the 4 g-groups (same i=l16), then store O[i][d]
  l_ += __shfl_xor(l_, 16);
  l_ += __shfl_xor(l_, 32);
  const float inv = 1.0f / l_;
  unsigned short* op = O + (size_t)(bb * SEQ + i_base + l16) * EMBED + hh * HD;
#pragma unroll
  for (int db = 0; db < 4; ++db) {
    u32x2 o;
    o[0] = cvtpk(accd[db][0] * inv, accd[db][1] * inv);
    o[1] = cvtpk(accd[db][2] * inv, accd[db][3] * inv);
    *reinterpret_cast<u32x2*>(op + db * 16 + g * 4) = o;
  }
#undef STAGE
}

// ---------------------------------------------------------------- launcher
extern "C" void kernel_launch(void* const* d_in, const int* in_sizes, int n_in,
                              void* d_out, int out_size, void* d_ws, size_t ws_size,
                              hipStream_t stream) {
  const float* x = (const float*)d_in[0];
  const float* Wq = (const float*)d_in[1];
  const float* Wk = (const float*)d_in[2];
  const float* Wv = (const float*)d_in[3];
  const float* Wo = (const float*)d_in[4];
  const float* Wf = (const float*)d_in[5];
  float* out = (float*)d_out;

  char* ws = (char*)d_ws;
  const size_t SZ_X = (size_t)ROWS * EMBED * sizeof(unsigned short);
  const size_t SZ_W = (size_t)EMBED * EMBED * sizeof(unsigned short);
  const size_t SZ_WF = (size_t)NHEAD * EMBED * sizeof(unsigned short);
  unsigned short* xb = (unsigned short*)ws;   ws += SZ_X;
  unsigned short* xlo = (unsigned short*)ws;  ws += SZ_X;
  unsigned short* Wqb = (unsigned short*)ws;  ws += SZ_W;
  unsigned short* Wkb = (unsigned short*)ws;  ws += SZ_W;
  unsigned short* Wvb = (unsigned short*)ws;  ws += SZ_W;
  unsigned short* Wob = (unsigned short*)ws;  ws += SZ_W;
  unsigned short* Wfh = (unsigned short*)ws;  ws += SZ_WF;
  unsigned short* Wfl = (unsigned short*)ws;  ws += SZ_WF;
  unsigned short* Qb = (unsigned short*)ws;   ws += SZ_X;
  unsigned short* Kb = (unsigned short*)ws;   ws += SZ_X;
  unsigned short* Vb = (unsigned short*)ws;   ws += SZ_X;
  unsigned short* attnb = (unsigned short*)ws; ws += SZ_X;
  float* carr = (float*)ws;                   ws += (size_t)BATCH * NHEAD * SEQ * sizeof(float);
  float* qkmax = (float*)ws;                  ws += 64 * sizeof(float);

  cvt_all_kernel<<<dim3(1024, 6), 256, 0, stream>>>(
      x, Wq, Wk, Wv, Wo, Wf, xb, xlo, Wqb, Wkb, Wvb, Wob, Wfh, Wfl,
      (unsigned*)qkmax);

  // gate: split-K MFMA, 256 blocks (one 16-row tile per block, 4 waves over K)
  gate_kernel<<<256, 256, 0, stream>>>(xb, xlo, Wfh, Wfl, carr);

  // QKV projections: 256x256 8-phase kernel, fused maxabs (plain grid mapping)
  gemm256_kernel<true><<<dim3(12, 16), 512, 0, stream>>>(
      xb, Wqb, Wkb, Wvb, Qb, Kb, Vb, (unsigned*)qkmax);

  cumsum_kernel<<<BATCH * NHEAD, 64, 0, stream>>>(carr);

  // attention: QBLK=64, 1024 blocks (128 per XCD)
  fa_attn_kernel<<<1024, 256, 0, stream>>>(Qb, Kb, Vb, carr, qkmax, attnb);

  // Wo: 64x128 tiles, 512 blocks = 2 blocks/CU (occupancy overlap)
  gemm_wo_kernel<<<dim3(8, 64), 256, 0, stream>>>(attnb, Wob, out);
}